// Round 4
// baseline (950.654 us; speedup 1.0000x reference)
//
#include <hip/hip_runtime.h>
#include <hip/hip_bf16.h>
#include <math.h>

#define N_NODES 100000
#define N_EDGES 1600000
#define F_IN 100
#define H 64
#define C 18
#define BSHIFT 7
#define NBUCKETS ((N_NODES + 127) >> BSHIFT)   // 782

// ----------------- bf16x2 pack/unpack -----------------

__device__ __forceinline__ unsigned bf16_rne(float f) {
    unsigned u = __float_as_uint(f);
    return (u + 0x7FFFu + ((u >> 16) & 1u)) >> 16;
}
__device__ __forceinline__ unsigned pack_bf2(float a, float b) {
    return bf16_rne(a) | (bf16_rne(b) << 16);
}
__device__ __forceinline__ float2 unpack_bf2(unsigned u) {
    return make_float2(__uint_as_float(u << 16), __uint_as_float(u & 0xFFFF0000u));
}

// ----------------- CSR build -----------------

__global__ void hist_kernel(const int* __restrict__ tgt, int* __restrict__ cnt) {
    int i = blockIdx.x * blockDim.x + threadIdx.x;
    int stride = gridDim.x * blockDim.x;
    for (int e = i; e < N_EDGES; e += stride) atomicAdd(&cnt[tgt[e]], 1);
}

__global__ void scan1_kernel(const int* __restrict__ cnt, int* __restrict__ excl,
                             int* __restrict__ bsum) {
    __shared__ int tmp[256];
    int t = threadIdx.x;
    int i = blockIdx.x * 256 + t;
    int v = (i < N_NODES) ? cnt[i] : 0;
    tmp[t] = v;
    __syncthreads();
    for (int off = 1; off < 256; off <<= 1) {
        int xv = (t >= off) ? tmp[t - off] : 0;
        __syncthreads();
        tmp[t] += xv;
        __syncthreads();
    }
    if (i < N_NODES) excl[i] = tmp[t] - v;
    if (t == 255) bsum[blockIdx.x] = tmp[255];
}

__global__ void scan2_kernel(int* bsum, int nb) {
    if (blockIdx.x == 0 && threadIdx.x == 0) {
        int run = 0;
        for (int j = 0; j < nb; ++j) { int v = bsum[j]; bsum[j] = run; run += v; }
    }
}

__global__ void scan3_kernel(int* __restrict__ rp, const int* __restrict__ bsum) {
    int i = blockIdx.x * 256 + threadIdx.x;
    if (i < N_NODES) rp[i] += bsum[i >> 8];
    if (i == N_NODES) rp[N_NODES] = N_EDGES;
}

__global__ void dinv_kernel(const int* __restrict__ cnt, float* __restrict__ dinv) {
    int i = blockIdx.x * blockDim.x + threadIdx.x;
    if (i < N_NODES) {
        int c = cnt[i];
        dinv[i] = (c > 0) ? rsqrtf((float)c) : 0.0f;
    }
}

// pass 1: scatter edges to their (aligned) bucket region; bucket start = rp[b<<7].
// packed word = src | (t_local << 17)   (src < 2^17, t_local < 128)
__global__ void bucket1_kernel(const int* __restrict__ src, const int* __restrict__ tgt,
                               const int* __restrict__ rp, int* __restrict__ bcur,
                               unsigned* __restrict__ tmp) {
    int i = blockIdx.x * blockDim.x + threadIdx.x;
    int stride = gridDim.x * blockDim.x;
    for (int e = i; e < N_EDGES; e += stride) {
        int s = src[e], t = tgt[e];
        int b = t >> BSHIFT;
        int pos = rp[b << BSHIFT] + atomicAdd(&bcur[b], 1);
        tmp[pos] = (unsigned)s | ((unsigned)(t & 127) << 17);
    }
}

// pass 2: one block per bucket; LDS cursors; final writes land in an ~8KB window.
__global__ void __launch_bounds__(256) bucket2_kernel(
        const unsigned* __restrict__ tmp, const int* __restrict__ rp,
        int* __restrict__ ssrc) {
    __shared__ int rpl[129];
    __shared__ int cur[128];
    int b = blockIdx.x;
    int n_lo = b << BSHIFT;
    int n_hi = min(n_lo + 128, N_NODES);
    int nn = n_hi - n_lo;
    int t = threadIdx.x;
    if (t < nn) { rpl[t] = rp[n_lo + t]; cur[t] = 0; }
    if (t == 0) rpl[nn] = rp[n_hi];
    __syncthreads();
    int e_lo = rpl[0], e_hi = rpl[nn];
    for (int e = e_lo + t; e < e_hi; e += 256) {
        unsigned p = tmp[e];
        int s = (int)(p & 0x1FFFFu);
        int tl = (int)(p >> 17);
        int pos = rpl[tl] + atomicAdd(&cur[tl], 1);
        ssrc[pos] = s;
    }
}

// ----------------- dense mixes (LDS-staged activations, bf16x2 outputs) -----------------

// g[n*64+lane] = pack(dinv*sum x*Wi k0, k1);  root[n*64+lane] = pack(sum x*Wr k0, k1)
__global__ void __launch_bounds__(256) dense1_kernel(
        const float* __restrict__ x, const float* __restrict__ Wi,
        const float* __restrict__ Wr, const float* __restrict__ dinv,
        unsigned* __restrict__ g, unsigned* __restrict__ root) {
    __shared__ float xs[64 * F_IN];
    int tid = threadIdx.x;
    int b0 = blockIdx.x * 64;
    int valid = min(64, N_NODES - b0);
    const float4* xg4 = (const float4*)(x + (size_t)b0 * F_IN);
    float4* xs4 = (float4*)xs;
    int cnt4 = valid * (F_IN / 4);
    for (int i = tid; i < cnt4; i += 256) xs4[i] = xg4[i];
    __syncthreads();
    int lane = tid & 63;
    int n0 = (tid >> 6) * 16;
    if (b0 + n0 >= N_NODES) return;
    float ai0[16], ai1[16], ar0[16], ar1[16];
    #pragma unroll
    for (int n = 0; n < 16; ++n) { ai0[n]=0.f; ai1[n]=0.f; ar0[n]=0.f; ar1[n]=0.f; }
    const float2* xs2 = (const float2*)xs;
    for (int fp = 0; fp < F_IN / 2; ++fp) {
        int f = 2 * fp;
        float wi00 = Wi[f * H + lane],            wi01 = Wi[(f + 1) * H + lane];
        float wi10 = Wi[(F_IN + f) * H + lane],   wi11 = Wi[(F_IN + f + 1) * H + lane];
        float wr00 = Wr[f * H + lane],            wr01 = Wr[(f + 1) * H + lane];
        float wr10 = Wr[(F_IN + f) * H + lane],   wr11 = Wr[(F_IN + f + 1) * H + lane];
        #pragma unroll
        for (int n = 0; n < 16; ++n) {
            float2 xv = xs2[(n0 + n) * (F_IN / 2) + fp];
            ai0[n] = fmaf(xv.x, wi00, ai0[n]); ai0[n] = fmaf(xv.y, wi01, ai0[n]);
            ai1[n] = fmaf(xv.x, wi10, ai1[n]); ai1[n] = fmaf(xv.y, wi11, ai1[n]);
            ar0[n] = fmaf(xv.x, wr00, ar0[n]); ar0[n] = fmaf(xv.y, wr01, ar0[n]);
            ar1[n] = fmaf(xv.x, wr10, ar1[n]); ar1[n] = fmaf(xv.y, wr11, ar1[n]);
        }
    }
    #pragma unroll
    for (int n = 0; n < 16; ++n) {
        int gn = b0 + n0 + n;
        float dv = dinv[gn];
        g[(size_t)gn * H + lane]    = pack_bf2(dv * ai0[n], dv * ai1[n]);
        root[(size_t)gn * H + lane] = pack_bf2(ar0[n], ar1[n]);
    }
}

// hin fp32 interleaved [n][64][2] -> packed bf16x2 out, per-stack W [2][64][64]
__global__ void __launch_bounds__(256) dense_mid_kernel(
        const float2* __restrict__ hin, const float* __restrict__ W,
        const float* __restrict__ dinv, unsigned* __restrict__ out) {
    __shared__ float2 hs[64 * H];   // 32 KB
    int tid = threadIdx.x;
    int b0 = blockIdx.x * 64;
    int valid = min(64, N_NODES - b0);
    const float4* src4 = (const float4*)(hin + (size_t)b0 * H);
    float4* dst4 = (float4*)hs;
    int cnt4 = valid * (H / 2);
    for (int i = tid; i < cnt4; i += 256) dst4[i] = src4[i];
    __syncthreads();
    int lane = tid & 63;
    int n0 = (tid >> 6) * 16;
    if (b0 + n0 >= N_NODES) return;
    float a0[16], a1[16];
    #pragma unroll
    for (int n = 0; n < 16; ++n) { a0[n] = 0.f; a1[n] = 0.f; }
    for (int f = 0; f < H; ++f) {
        float w0 = W[f * H + lane];
        float w1v = W[H * H + f * H + lane];
        #pragma unroll
        for (int n = 0; n < 16; ++n) {
            float2 xv = hs[(n0 + n) * H + f];
            a0[n] = fmaf(xv.x, w0, a0[n]);
            a1[n] = fmaf(xv.y, w1v, a1[n]);
        }
    }
    #pragma unroll
    for (int n = 0; n < 16; ++n) {
        int gn = b0 + n0 + n;
        float dv = dinv[gn];
        out[(size_t)gn * H + lane] = pack_bf2(dv * a0[n], dv * a1[n]);
    }
}

// y planar fp32 [n][64] -> h2/root2 packed bf16x2 [n][18]
__global__ void __launch_bounds__(256) dense_y2_kernel(
        const float* __restrict__ y, const float* __restrict__ Wi,
        const float* __restrict__ Wr, const float* __restrict__ dinv,
        unsigned* __restrict__ h2, unsigned* __restrict__ root2) {
    __shared__ float ys[64 * H];    // 16 KB
    int tid = threadIdx.x;
    int b0 = blockIdx.x * 64;
    int valid = min(64, N_NODES - b0);
    const float4* src4 = (const float4*)(y + (size_t)b0 * H);
    float4* dst4 = (float4*)ys;
    int cnt4 = valid * (H / 4);
    for (int i = tid; i < cnt4; i += 256) dst4[i] = src4[i];
    __syncthreads();
    int lane = tid & 63;
    int n0 = (tid >> 6) * 16;
    if (b0 + n0 >= N_NODES) return;
    bool act = lane < C;
    int c = act ? lane : 0;
    float ah0[16], ah1[16], ar0[16], ar1[16];
    #pragma unroll
    for (int n = 0; n < 16; ++n) { ah0[n]=0.f; ah1[n]=0.f; ar0[n]=0.f; ar1[n]=0.f; }
    const float2* ys2 = (const float2*)ys;
    for (int fp = 0; fp < H / 2; ++fp) {
        int f = 2 * fp;
        float wi00 = Wi[f * C + c],        wi01 = Wi[(f + 1) * C + c];
        float wi10 = Wi[(H + f) * C + c],  wi11 = Wi[(H + f + 1) * C + c];
        float wr00 = Wr[f * C + c],        wr01 = Wr[(f + 1) * C + c];
        float wr10 = Wr[(H + f) * C + c],  wr11 = Wr[(H + f + 1) * C + c];
        #pragma unroll
        for (int n = 0; n < 16; ++n) {
            float2 xv = ys2[(n0 + n) * (H / 2) + fp];
            ah0[n] = fmaf(xv.x, wi00, ah0[n]); ah0[n] = fmaf(xv.y, wi01, ah0[n]);
            ah1[n] = fmaf(xv.x, wi10, ah1[n]); ah1[n] = fmaf(xv.y, wi11, ah1[n]);
            ar0[n] = fmaf(xv.x, wr00, ar0[n]); ar0[n] = fmaf(xv.y, wr01, ar0[n]);
            ar1[n] = fmaf(xv.x, wr10, ar1[n]); ar1[n] = fmaf(xv.y, wr11, ar1[n]);
        }
    }
    if (act) {
        #pragma unroll
        for (int n = 0; n < 16; ++n) {
            int gn = b0 + n0 + n;
            float dv = dinv[gn];
            h2[(size_t)gn * C + c]    = pack_bf2(dv * ah0[n], dv * ah1[n]);
            root2[(size_t)gn * C + c] = pack_bf2(ar0[n], ar1[n]);
        }
    }
}

// hin fp32 interleaved [n][18][2] -> packed bf16x2 out, W [2][18][18]
__global__ void __launch_bounds__(256) dense_last_kernel(
        const float2* __restrict__ hin, const float* __restrict__ W,
        const float* __restrict__ dinv, unsigned* __restrict__ out) {
    __shared__ float2 hs[64 * C];   // 9.2 KB
    int tid = threadIdx.x;
    int b0 = blockIdx.x * 64;
    int valid = min(64, N_NODES - b0);
    const float4* src4 = (const float4*)(hin + (size_t)b0 * C);
    float4* dst4 = (float4*)hs;
    int cnt4 = valid * C / 2;
    for (int i = tid; i < cnt4; i += 256) dst4[i] = src4[i];
    __syncthreads();
    int lane = tid & 63;
    int n0 = (tid >> 6) * 16;
    if (b0 + n0 >= N_NODES) return;
    bool act = lane < C;
    int c = act ? lane : 0;
    float a0[16], a1[16];
    #pragma unroll
    for (int n = 0; n < 16; ++n) { a0[n] = 0.f; a1[n] = 0.f; }
    #pragma unroll
    for (int j = 0; j < C; ++j) {
        float w0 = W[j * C + c];
        float w1v = W[C * C + j * C + c];
        #pragma unroll
        for (int n = 0; n < 16; ++n) {
            float2 xv = hs[(n0 + n) * C + j];
            a0[n] = fmaf(xv.x, w0, a0[n]);
            a1[n] = fmaf(xv.y, w1v, a1[n]);
        }
    }
    if (act) {
        #pragma unroll
        for (int n = 0; n < 16; ++n) {
            int gn = b0 + n0 + n;
            float dv = dinv[gn];
            out[(size_t)gn * C + c] = pack_bf2(dv * a0[n], dv * a1[n]);
        }
    }
}

// ----------------- propagation (gather over CSR, bf16x2 stacks) -----------------
// g is PRE-SCALED by dinv[src]; epilogue applies dinv[tgt]. One wave/node.

template <int FINAL>
__global__ void __launch_bounds__(256) prop64_kernel(
        const unsigned* __restrict__ g, const unsigned* __restrict__ root,
        const float* __restrict__ b, const float* __restrict__ dinv,
        const int* __restrict__ rp, const int* __restrict__ ssrc,
        float2* __restrict__ out2, float* __restrict__ outp) {
    int lane = threadIdx.x & 63;
    int wid = __builtin_amdgcn_readfirstlane((int)((blockIdx.x * 256 + threadIdx.x) >> 6));
    if (wid >= N_NODES) return;
    int e0 = rp[wid], e1 = rp[wid + 1];
    float a0 = 0.f, a1 = 0.f;
    int e = e0;
    for (; e + 4 <= e1; e += 4) {
        int s0 = ssrc[e], s1 = ssrc[e + 1], s2 = ssrc[e + 2], s3 = ssrc[e + 3];
        unsigned u0 = g[(size_t)s0 * H + lane];
        unsigned u1 = g[(size_t)s1 * H + lane];
        unsigned u2 = g[(size_t)s2 * H + lane];
        unsigned u3 = g[(size_t)s3 * H + lane];
        float2 v0 = unpack_bf2(u0), v1 = unpack_bf2(u1);
        float2 v2 = unpack_bf2(u2), v3 = unpack_bf2(u3);
        a0 += (v0.x + v1.x) + (v2.x + v3.x);
        a1 += (v0.y + v1.y) + (v2.y + v3.y);
    }
    for (; e < e1; ++e) {
        float2 v = unpack_bf2(g[(size_t)ssrc[e] * H + lane]);
        a0 += v.x; a1 += v.y;
    }
    float dv = dinv[wid];
    float2 rt = unpack_bf2(root[(size_t)wid * H + lane]);
    float o0 = fmaxf(fmaf(dv, a0, rt.x + b[lane]), 0.f);
    float o1 = fmaxf(fmaf(dv, a1, rt.y + b[H + lane]), 0.f);
    if (FINAL) {
        outp[(size_t)wid * H + lane] = 0.5f * (o0 + o1);
    } else {
        out2[(size_t)wid * H + lane] = make_float2(o0, o1);
    }
}

template <int FINAL>
__global__ void __launch_bounds__(256) prop18_kernel(
        const unsigned* __restrict__ g, const unsigned* __restrict__ root,
        const float* __restrict__ b, const float* __restrict__ dinv,
        const int* __restrict__ rp, const int* __restrict__ ssrc,
        float2* __restrict__ out2, float* __restrict__ outp) {
    int lane = threadIdx.x & 63;
    int wid = __builtin_amdgcn_readfirstlane((int)((blockIdx.x * 256 + threadIdx.x) >> 6));
    if (wid >= N_NODES) return;
    int e0 = rp[wid], e1 = rp[wid + 1];
    bool act = lane < C;
    int c = act ? lane : 0;
    float a0 = 0.f, a1 = 0.f;
    int e = e0;
    for (; e + 4 <= e1; e += 4) {
        int s0 = ssrc[e], s1 = ssrc[e + 1], s2 = ssrc[e + 2], s3 = ssrc[e + 3];
        unsigned u0 = g[(size_t)s0 * C + c];
        unsigned u1 = g[(size_t)s1 * C + c];
        unsigned u2 = g[(size_t)s2 * C + c];
        unsigned u3 = g[(size_t)s3 * C + c];
        float2 v0 = unpack_bf2(u0), v1 = unpack_bf2(u1);
        float2 v2 = unpack_bf2(u2), v3 = unpack_bf2(u3);
        if (act) {
            a0 += (v0.x + v1.x) + (v2.x + v3.x);
            a1 += (v0.y + v1.y) + (v2.y + v3.y);
        }
    }
    for (; e < e1; ++e) {
        float2 v = unpack_bf2(g[(size_t)ssrc[e] * C + c]);
        if (act) { a0 += v.x; a1 += v.y; }
    }
    float dv = dinv[wid];
    float o0 = 0.f, o1 = 0.f;
    if (act) {
        float2 rt = unpack_bf2(root[(size_t)wid * C + c]);
        o0 = fmaxf(fmaf(dv, a0, rt.x + b[c]), 0.f);
        o1 = fmaxf(fmaf(dv, a1, rt.y + b[C + c]), 0.f);
    }
    if (!FINAL) {
        if (act) out2[(size_t)wid * C + c] = make_float2(o0, o1);
    } else {
        float m = act ? 0.5f * (o0 + o1) : -INFINITY;
        float mx = m;
        #pragma unroll
        for (int off = 16; off >= 1; off >>= 1) mx = fmaxf(mx, __shfl_xor(mx, off, 64));
        float ex = act ? __expf(m - mx) : 0.f;
        float sum = ex;
        #pragma unroll
        for (int off = 16; off >= 1; off >>= 1) sum += __shfl_xor(sum, off, 64);
        if (act) outp[(size_t)wid * C + c] = m - mx - logf(sum);
    }
}

// ----------------- launch -----------------

extern "C" void kernel_launch(void* const* d_in, const int* in_sizes, int n_in,
                              void* d_out, int out_size, void* d_ws, size_t ws_size,
                              hipStream_t stream) {
    const float* x        = (const float*)d_in[0];
    const int*   ei       = (const int*)d_in[1];
    const float* init_w1  = (const float*)d_in[2];
    const float* w1       = (const float*)d_in[3];
    const float* root_w1  = (const float*)d_in[4];
    const float* b1       = (const float*)d_in[5];
    const float* init_w2  = (const float*)d_in[6];
    const float* w2       = (const float*)d_in[7];
    const float* root_w2  = (const float*)d_in[8];
    const float* b2       = (const float*)d_in[9];
    const int* src = ei;
    const int* tgt = ei + N_EDGES;
    float* out = (float*)d_out;

    char* w = (char*)d_ws;
    size_t off = 0;
    auto alloc = [&](size_t bytes) -> char* {
        char* p = w + off;
        off += (bytes + 255) & ~(size_t)255;
        return p;
    };
    int*      cnt   = (int*)alloc((size_t)N_NODES * 4);
    int*      rp    = (int*)alloc((size_t)(N_NODES + 1) * 4);
    int*      bcur  = (int*)alloc((size_t)NBUCKETS * 4);
    float*    dinv  = (float*)alloc((size_t)N_NODES * 4);
    int*      bsum  = (int*)alloc(512 * 4);
    unsigned* tmp   = (unsigned*)alloc((size_t)N_EDGES * 4);
    int*      ssrc  = (int*)alloc((size_t)N_EDGES * 4);
    unsigned* g1    = (unsigned*)alloc((size_t)N_NODES * H * 4);   // 25.6 MB
    unsigned* root1 = (unsigned*)alloc((size_t)N_NODES * H * 4);   // 25.6 MB
    float2*   hB2   = (float2*)alloc((size_t)N_NODES * H * 8);     // 51.2 MB
    unsigned* g2    = (unsigned*)alloc((size_t)N_NODES * H * 4);   // 25.6 MB
    float*    y     = (float*)alloc((size_t)N_NODES * H * 4);      // 25.6 MB
    // layer-2 overlays (lifetimes disjoint from g1/root1 gather use)
    unsigned* h2u    = g1;                                          // N*C
    unsigned* root2u = g1 + (size_t)N_NODES * C;                    // N*C
    unsigned* h3u    = g1 + (size_t)2 * N_NODES * C;                // N*C
    float2*   h2o    = (float2*)root1;                              // N*C float2

    hipMemsetAsync(cnt, 0, (size_t)N_NODES * 4, stream);
    hipMemsetAsync(bcur, 0, (size_t)NBUCKETS * 4, stream);

    int nb = (N_NODES + 255) / 256;  // 391
    hist_kernel<<<1024, 256, 0, stream>>>(tgt, cnt);
    scan1_kernel<<<nb, 256, 0, stream>>>(cnt, rp, bsum);
    scan2_kernel<<<1, 64, 0, stream>>>(bsum, nb);
    scan3_kernel<<<(N_NODES + 1 + 255) / 256, 256, 0, stream>>>(rp, bsum);
    dinv_kernel<<<(N_NODES + 255) / 256, 256, 0, stream>>>(cnt, dinv);
    bucket1_kernel<<<1024, 256, 0, stream>>>(src, tgt, rp, bcur, tmp);
    bucket2_kernel<<<NBUCKETS, 256, 0, stream>>>(tmp, rp, ssrc);

    int gblocks = (N_NODES + 63) / 64;          // 1563
    int pgrid   = (N_NODES + 3) / 4;            // 25000 (wave per node)

    // ---- layer 1 (F_IN=100 -> H=64) ----
    dense1_kernel<<<gblocks, 256, 0, stream>>>(x, init_w1, root_w1, dinv, g1, root1);
    prop64_kernel<0><<<pgrid, 256, 0, stream>>>(g1, root1, b1, dinv, rp, ssrc, hB2, nullptr);
    dense_mid_kernel<<<gblocks, 256, 0, stream>>>(hB2, w1, dinv, g2);
    prop64_kernel<1><<<pgrid, 256, 0, stream>>>(g2, root1, b1, dinv, rp, ssrc, nullptr, y);

    // ---- layer 2 (H=64 -> C=18) ----
    dense_y2_kernel<<<gblocks, 256, 0, stream>>>(y, init_w2, root_w2, dinv, h2u, root2u);
    prop18_kernel<0><<<pgrid, 256, 0, stream>>>(h2u, root2u, b2, dinv, rp, ssrc, h2o, nullptr);
    dense_last_kernel<<<gblocks, 256, 0, stream>>>(h2o, w2, dinv, h3u);
    prop18_kernel<1><<<pgrid, 256, 0, stream>>>(h3u, root2u, b2, dinv, rp, ssrc, nullptr, out);
}

// Round 5
// 641.530 us; speedup vs baseline: 1.4819x; 1.4819x over previous
//
#include <hip/hip_runtime.h>
#include <hip/hip_bf16.h>
#include <math.h>

#define N_NODES 100000
#define N_EDGES 1600000
#define F_IN 100
#define H 64
#define C 18
#define BSHIFT 8
#define BSIZE 256
#define NBUCKETS ((N_NODES + BSIZE - 1) >> BSHIFT)   // 391
#define NBLK 256
#define CHUNK (N_EDGES / NBLK)                       // 6250

// ----------------- bf16x2 pack/unpack -----------------

__device__ __forceinline__ unsigned bf16_rne(float f) {
    unsigned u = __float_as_uint(f);
    return (u + 0x7FFFu + ((u >> 16) & 1u)) >> 16;
}
__device__ __forceinline__ unsigned pack_bf2(float a, float b) {
    return bf16_rne(a) | (bf16_rne(b) << 16);
}
__device__ __forceinline__ float2 unpack_bf2(unsigned u) {
    return make_float2(__uint_as_float(u << 16), __uint_as_float(u & 0xFFFF0000u));
}

// ----------------- CSR build -----------------

__global__ void hist_kernel(const int* __restrict__ tgt, int* __restrict__ cnt) {
    int i = blockIdx.x * blockDim.x + threadIdx.x;
    int stride = gridDim.x * blockDim.x;
    for (int e = i; e < N_EDGES; e += stride) atomicAdd(&cnt[tgt[e]], 1);
}

// generalized 3-kernel exclusive scan: excl = exclusive_scan(cnt[0..n))
__global__ void scan1_kernel(const int* __restrict__ cnt, int* __restrict__ excl,
                             int* __restrict__ bsum, int n) {
    __shared__ int tmp[256];
    int t = threadIdx.x;
    int i = blockIdx.x * 256 + t;
    int v = (i < n) ? cnt[i] : 0;
    tmp[t] = v;
    __syncthreads();
    for (int off = 1; off < 256; off <<= 1) {
        int xv = (t >= off) ? tmp[t - off] : 0;
        __syncthreads();
        tmp[t] += xv;
        __syncthreads();
    }
    if (i < n) excl[i] = tmp[t] - v;
    if (t == 255) bsum[blockIdx.x] = tmp[255];
}

__global__ void scan2_kernel(int* bsum, int nb) {
    if (blockIdx.x == 0 && threadIdx.x == 0) {
        int run = 0;
        for (int j = 0; j < nb; ++j) { int v = bsum[j]; bsum[j] = run; run += v; }
    }
}

// adds block offsets; optionally writes sentinel arr[n] = sent (if sent >= 0)
__global__ void scan3_kernel(int* __restrict__ arr, const int* __restrict__ bsum,
                             int n, int sent) {
    int i = blockIdx.x * 256 + threadIdx.x;
    if (i < n) arr[i] += bsum[i >> 8];
    if (i == n && sent >= 0) arr[n] = sent;
}

__global__ void dinv_kernel(const int* __restrict__ cnt, float* __restrict__ dinv) {
    int i = blockIdx.x * blockDim.x + threadIdx.x;
    if (i < N_NODES) {
        int c = cnt[i];
        dinv[i] = (c > 0) ? rsqrtf((float)c) : 0.0f;
    }
}

// Pass A: per-(bucket, block) histogram. No global atomics.
__global__ void __launch_bounds__(256) histA_kernel(const int* __restrict__ tgt,
                                                    int* __restrict__ hist) {
    __shared__ int h[NBUCKETS];
    int blk = blockIdx.x, t = threadIdx.x;
    for (int i = t; i < NBUCKETS; i += 256) h[i] = 0;
    __syncthreads();
    int e0 = blk * CHUNK, e1 = e0 + CHUNK;
    for (int e = e0 + t; e < e1; e += 256) atomicAdd(&h[tgt[e] >> BSHIFT], 1);
    __syncthreads();
    for (int i = t; i < NBUCKETS; i += 256) hist[i * NBLK + blk] = h[i];
}

// Pass C: scatter edges to exact positions (block-local LDS cursors only).
// packed word = src | (t_local << 17)   (src < 2^17, t_local < 256)
__global__ void __launch_bounds__(256) scatterC_kernel(
        const int* __restrict__ src, const int* __restrict__ tgt,
        const int* __restrict__ histx, unsigned* __restrict__ tmp) {
    __shared__ int cur[NBUCKETS];
    int blk = blockIdx.x, t = threadIdx.x;
    for (int i = t; i < NBUCKETS; i += 256) cur[i] = histx[i * NBLK + blk];
    __syncthreads();
    int e0 = blk * CHUNK, e1 = e0 + CHUNK;
    for (int e = e0 + t; e < e1; e += 256) {
        int s = src[e], tg = tgt[e];
        int b = tg >> BSHIFT;
        int pos = atomicAdd(&cur[b], 1);
        tmp[pos] = (unsigned)s | ((unsigned)(tg & (BSIZE - 1)) << 17);
    }
}

// Pass D: one block per bucket; final ssrc writes land in a ~16KB window.
__global__ void __launch_bounds__(256) bucketD_kernel(
        const unsigned* __restrict__ tmp, const int* __restrict__ rp,
        int* __restrict__ ssrc) {
    __shared__ int rpl[BSIZE + 1];
    __shared__ int cur[BSIZE];
    int b = blockIdx.x;
    int n_lo = b << BSHIFT;
    int n_hi = min(n_lo + BSIZE, N_NODES);
    int nn = n_hi - n_lo;
    int t = threadIdx.x;
    if (t < nn) { rpl[t] = rp[n_lo + t]; cur[t] = 0; }
    if (t == 0) rpl[nn] = rp[n_hi];
    __syncthreads();
    int e_lo = rpl[0], e_hi = rpl[nn];
    for (int e = e_lo + t; e < e_hi; e += 256) {
        unsigned p = tmp[e];
        int s = (int)(p & 0x1FFFFu);
        int tl = (int)(p >> 17);
        int pos = rpl[tl] + atomicAdd(&cur[tl], 1);
        ssrc[pos] = s;
    }
}

// ----------------- dense mixes (LDS-staged activations, bf16x2 outputs) -----------------

__global__ void __launch_bounds__(256) dense1_kernel(
        const float* __restrict__ x, const float* __restrict__ Wi,
        const float* __restrict__ Wr, const float* __restrict__ dinv,
        unsigned* __restrict__ g, unsigned* __restrict__ root) {
    __shared__ float xs[64 * F_IN];
    int tid = threadIdx.x;
    int b0 = blockIdx.x * 64;
    int valid = min(64, N_NODES - b0);
    const float4* xg4 = (const float4*)(x + (size_t)b0 * F_IN);
    float4* xs4 = (float4*)xs;
    int cnt4 = valid * (F_IN / 4);
    for (int i = tid; i < cnt4; i += 256) xs4[i] = xg4[i];
    __syncthreads();
    int lane = tid & 63;
    int n0 = (tid >> 6) * 16;
    if (b0 + n0 >= N_NODES) return;
    float ai0[16], ai1[16], ar0[16], ar1[16];
    #pragma unroll
    for (int n = 0; n < 16; ++n) { ai0[n]=0.f; ai1[n]=0.f; ar0[n]=0.f; ar1[n]=0.f; }
    const float2* xs2 = (const float2*)xs;
    for (int fp = 0; fp < F_IN / 2; ++fp) {
        int f = 2 * fp;
        float wi00 = Wi[f * H + lane],            wi01 = Wi[(f + 1) * H + lane];
        float wi10 = Wi[(F_IN + f) * H + lane],   wi11 = Wi[(F_IN + f + 1) * H + lane];
        float wr00 = Wr[f * H + lane],            wr01 = Wr[(f + 1) * H + lane];
        float wr10 = Wr[(F_IN + f) * H + lane],   wr11 = Wr[(F_IN + f + 1) * H + lane];
        #pragma unroll
        for (int n = 0; n < 16; ++n) {
            float2 xv = xs2[(n0 + n) * (F_IN / 2) + fp];
            ai0[n] = fmaf(xv.x, wi00, ai0[n]); ai0[n] = fmaf(xv.y, wi01, ai0[n]);
            ai1[n] = fmaf(xv.x, wi10, ai1[n]); ai1[n] = fmaf(xv.y, wi11, ai1[n]);
            ar0[n] = fmaf(xv.x, wr00, ar0[n]); ar0[n] = fmaf(xv.y, wr01, ar0[n]);
            ar1[n] = fmaf(xv.x, wr10, ar1[n]); ar1[n] = fmaf(xv.y, wr11, ar1[n]);
        }
    }
    #pragma unroll
    for (int n = 0; n < 16; ++n) {
        int gn = b0 + n0 + n;
        float dv = dinv[gn];
        g[(size_t)gn * H + lane]    = pack_bf2(dv * ai0[n], dv * ai1[n]);
        root[(size_t)gn * H + lane] = pack_bf2(ar0[n], ar1[n]);
    }
}

__global__ void __launch_bounds__(256) dense_mid_kernel(
        const float2* __restrict__ hin, const float* __restrict__ W,
        const float* __restrict__ dinv, unsigned* __restrict__ out) {
    __shared__ float2 hs[64 * H];   // 32 KB
    int tid = threadIdx.x;
    int b0 = blockIdx.x * 64;
    int valid = min(64, N_NODES - b0);
    const float4* src4 = (const float4*)(hin + (size_t)b0 * H);
    float4* dst4 = (float4*)hs;
    int cnt4 = valid * (H / 2);
    for (int i = tid; i < cnt4; i += 256) dst4[i] = src4[i];
    __syncthreads();
    int lane = tid & 63;
    int n0 = (tid >> 6) * 16;
    if (b0 + n0 >= N_NODES) return;
    float a0[16], a1[16];
    #pragma unroll
    for (int n = 0; n < 16; ++n) { a0[n] = 0.f; a1[n] = 0.f; }
    for (int f = 0; f < H; ++f) {
        float w0 = W[f * H + lane];
        float w1v = W[H * H + f * H + lane];
        #pragma unroll
        for (int n = 0; n < 16; ++n) {
            float2 xv = hs[(n0 + n) * H + f];
            a0[n] = fmaf(xv.x, w0, a0[n]);
            a1[n] = fmaf(xv.y, w1v, a1[n]);
        }
    }
    #pragma unroll
    for (int n = 0; n < 16; ++n) {
        int gn = b0 + n0 + n;
        float dv = dinv[gn];
        out[(size_t)gn * H + lane] = pack_bf2(dv * a0[n], dv * a1[n]);
    }
}

__global__ void __launch_bounds__(256) dense_y2_kernel(
        const float* __restrict__ y, const float* __restrict__ Wi,
        const float* __restrict__ Wr, const float* __restrict__ dinv,
        unsigned* __restrict__ h2, unsigned* __restrict__ root2) {
    __shared__ float ys[64 * H];    // 16 KB
    int tid = threadIdx.x;
    int b0 = blockIdx.x * 64;
    int valid = min(64, N_NODES - b0);
    const float4* src4 = (const float4*)(y + (size_t)b0 * H);
    float4* dst4 = (float4*)ys;
    int cnt4 = valid * (H / 4);
    for (int i = tid; i < cnt4; i += 256) dst4[i] = src4[i];
    __syncthreads();
    int lane = tid & 63;
    int n0 = (tid >> 6) * 16;
    if (b0 + n0 >= N_NODES) return;
    bool act = lane < C;
    int c = act ? lane : 0;
    float ah0[16], ah1[16], ar0[16], ar1[16];
    #pragma unroll
    for (int n = 0; n < 16; ++n) { ah0[n]=0.f; ah1[n]=0.f; ar0[n]=0.f; ar1[n]=0.f; }
    const float2* ys2 = (const float2*)ys;
    for (int fp = 0; fp < H / 2; ++fp) {
        int f = 2 * fp;
        float wi00 = Wi[f * C + c],        wi01 = Wi[(f + 1) * C + c];
        float wi10 = Wi[(H + f) * C + c],  wi11 = Wi[(H + f + 1) * C + c];
        float wr00 = Wr[f * C + c],        wr01 = Wr[(f + 1) * C + c];
        float wr10 = Wr[(H + f) * C + c],  wr11 = Wr[(H + f + 1) * C + c];
        #pragma unroll
        for (int n = 0; n < 16; ++n) {
            float2 xv = ys2[(n0 + n) * (H / 2) + fp];
            ah0[n] = fmaf(xv.x, wi00, ah0[n]); ah0[n] = fmaf(xv.y, wi01, ah0[n]);
            ah1[n] = fmaf(xv.x, wi10, ah1[n]); ah1[n] = fmaf(xv.y, wi11, ah1[n]);
            ar0[n] = fmaf(xv.x, wr00, ar0[n]); ar0[n] = fmaf(xv.y, wr01, ar0[n]);
            ar1[n] = fmaf(xv.x, wr10, ar1[n]); ar1[n] = fmaf(xv.y, wr11, ar1[n]);
        }
    }
    if (act) {
        #pragma unroll
        for (int n = 0; n < 16; ++n) {
            int gn = b0 + n0 + n;
            float dv = dinv[gn];
            h2[(size_t)gn * C + c]    = pack_bf2(dv * ah0[n], dv * ah1[n]);
            root2[(size_t)gn * C + c] = pack_bf2(ar0[n], ar1[n]);
        }
    }
}

__global__ void __launch_bounds__(256) dense_last_kernel(
        const float2* __restrict__ hin, const float* __restrict__ W,
        const float* __restrict__ dinv, unsigned* __restrict__ out) {
    __shared__ float2 hs[64 * C];   // 9.2 KB
    int tid = threadIdx.x;
    int b0 = blockIdx.x * 64;
    int valid = min(64, N_NODES - b0);
    const float4* src4 = (const float4*)(hin + (size_t)b0 * C);
    float4* dst4 = (float4*)hs;
    int cnt4 = valid * C / 2;
    for (int i = tid; i < cnt4; i += 256) dst4[i] = src4[i];
    __syncthreads();
    int lane = tid & 63;
    int n0 = (tid >> 6) * 16;
    if (b0 + n0 >= N_NODES) return;
    bool act = lane < C;
    int c = act ? lane : 0;
    float a0[16], a1[16];
    #pragma unroll
    for (int n = 0; n < 16; ++n) { a0[n] = 0.f; a1[n] = 0.f; }
    #pragma unroll
    for (int j = 0; j < C; ++j) {
        float w0 = W[j * C + c];
        float w1v = W[C * C + j * C + c];
        #pragma unroll
        for (int n = 0; n < 16; ++n) {
            float2 xv = hs[(n0 + n) * C + j];
            a0[n] = fmaf(xv.x, w0, a0[n]);
            a1[n] = fmaf(xv.y, w1v, a1[n]);
        }
    }
    if (act) {
        #pragma unroll
        for (int n = 0; n < 16; ++n) {
            int gn = b0 + n0 + n;
            float dv = dinv[gn];
            out[(size_t)gn * C + c] = pack_bf2(dv * a0[n], dv * a1[n]);
        }
    }
}

// ----------------- propagation (gather over CSR, bf16x2 stacks) -----------------

template <int FINAL>
__global__ void __launch_bounds__(256) prop64_kernel(
        const unsigned* __restrict__ g, const unsigned* __restrict__ root,
        const float* __restrict__ b, const float* __restrict__ dinv,
        const int* __restrict__ rp, const int* __restrict__ ssrc,
        float2* __restrict__ out2, float* __restrict__ outp) {
    int lane = threadIdx.x & 63;
    int wid = __builtin_amdgcn_readfirstlane((int)((blockIdx.x * 256 + threadIdx.x) >> 6));
    if (wid >= N_NODES) return;
    int e0 = rp[wid], e1 = rp[wid + 1];
    float a0 = 0.f, a1 = 0.f;
    int e = e0;
    for (; e + 4 <= e1; e += 4) {
        int s0 = ssrc[e], s1 = ssrc[e + 1], s2 = ssrc[e + 2], s3 = ssrc[e + 3];
        unsigned u0 = g[(size_t)s0 * H + lane];
        unsigned u1 = g[(size_t)s1 * H + lane];
        unsigned u2 = g[(size_t)s2 * H + lane];
        unsigned u3 = g[(size_t)s3 * H + lane];
        float2 v0 = unpack_bf2(u0), v1 = unpack_bf2(u1);
        float2 v2 = unpack_bf2(u2), v3 = unpack_bf2(u3);
        a0 += (v0.x + v1.x) + (v2.x + v3.x);
        a1 += (v0.y + v1.y) + (v2.y + v3.y);
    }
    for (; e < e1; ++e) {
        float2 v = unpack_bf2(g[(size_t)ssrc[e] * H + lane]);
        a0 += v.x; a1 += v.y;
    }
    float dv = dinv[wid];
    float2 rt = unpack_bf2(root[(size_t)wid * H + lane]);
    float o0 = fmaxf(fmaf(dv, a0, rt.x + b[lane]), 0.f);
    float o1 = fmaxf(fmaf(dv, a1, rt.y + b[H + lane]), 0.f);
    if (FINAL) {
        outp[(size_t)wid * H + lane] = 0.5f * (o0 + o1);
    } else {
        out2[(size_t)wid * H + lane] = make_float2(o0, o1);
    }
}

template <int FINAL>
__global__ void __launch_bounds__(256) prop18_kernel(
        const unsigned* __restrict__ g, const unsigned* __restrict__ root,
        const float* __restrict__ b, const float* __restrict__ dinv,
        const int* __restrict__ rp, const int* __restrict__ ssrc,
        float2* __restrict__ out2, float* __restrict__ outp) {
    int lane = threadIdx.x & 63;
    int wid = __builtin_amdgcn_readfirstlane((int)((blockIdx.x * 256 + threadIdx.x) >> 6));
    if (wid >= N_NODES) return;
    int e0 = rp[wid], e1 = rp[wid + 1];
    bool act = lane < C;
    int c = act ? lane : 0;
    float a0 = 0.f, a1 = 0.f;
    int e = e0;
    for (; e + 4 <= e1; e += 4) {
        int s0 = ssrc[e], s1 = ssrc[e + 1], s2 = ssrc[e + 2], s3 = ssrc[e + 3];
        unsigned u0 = g[(size_t)s0 * C + c];
        unsigned u1 = g[(size_t)s1 * C + c];
        unsigned u2 = g[(size_t)s2 * C + c];
        unsigned u3 = g[(size_t)s3 * C + c];
        float2 v0 = unpack_bf2(u0), v1 = unpack_bf2(u1);
        float2 v2 = unpack_bf2(u2), v3 = unpack_bf2(u3);
        if (act) {
            a0 += (v0.x + v1.x) + (v2.x + v3.x);
            a1 += (v0.y + v1.y) + (v2.y + v3.y);
        }
    }
    for (; e < e1; ++e) {
        float2 v = unpack_bf2(g[(size_t)ssrc[e] * C + c]);
        if (act) { a0 += v.x; a1 += v.y; }
    }
    float dv = dinv[wid];
    float o0 = 0.f, o1 = 0.f;
    if (act) {
        float2 rt = unpack_bf2(root[(size_t)wid * C + c]);
        o0 = fmaxf(fmaf(dv, a0, rt.x + b[c]), 0.f);
        o1 = fmaxf(fmaf(dv, a1, rt.y + b[C + c]), 0.f);
    }
    if (!FINAL) {
        if (act) out2[(size_t)wid * C + c] = make_float2(o0, o1);
    } else {
        float m = act ? 0.5f * (o0 + o1) : -INFINITY;
        float mx = m;
        #pragma unroll
        for (int off = 16; off >= 1; off >>= 1) mx = fmaxf(mx, __shfl_xor(mx, off, 64));
        float ex = act ? __expf(m - mx) : 0.f;
        float sum = ex;
        #pragma unroll
        for (int off = 16; off >= 1; off >>= 1) sum += __shfl_xor(sum, off, 64);
        if (act) outp[(size_t)wid * C + c] = m - mx - logf(sum);
    }
}

// ----------------- launch -----------------

extern "C" void kernel_launch(void* const* d_in, const int* in_sizes, int n_in,
                              void* d_out, int out_size, void* d_ws, size_t ws_size,
                              hipStream_t stream) {
    const float* x        = (const float*)d_in[0];
    const int*   ei       = (const int*)d_in[1];
    const float* init_w1  = (const float*)d_in[2];
    const float* w1       = (const float*)d_in[3];
    const float* root_w1  = (const float*)d_in[4];
    const float* b1       = (const float*)d_in[5];
    const float* init_w2  = (const float*)d_in[6];
    const float* w2       = (const float*)d_in[7];
    const float* root_w2  = (const float*)d_in[8];
    const float* b2       = (const float*)d_in[9];
    const int* src = ei;
    const int* tgt = ei + N_EDGES;
    float* out = (float*)d_out;

    char* w = (char*)d_ws;
    size_t off = 0;
    auto alloc = [&](size_t bytes) -> char* {
        char* p = w + off;
        off += (bytes + 255) & ~(size_t)255;
        return p;
    };
    int*      cnt   = (int*)alloc((size_t)N_NODES * 4);
    int*      rp    = (int*)alloc((size_t)(N_NODES + 1) * 4);
    float*    dinv  = (float*)alloc((size_t)N_NODES * 4);
    int*      bsum  = (int*)alloc(512 * 4);
    int*      hist  = (int*)alloc((size_t)NBUCKETS * NBLK * 4);   // 0.4 MB
    int*      histx = (int*)alloc((size_t)NBUCKETS * NBLK * 4);   // 0.4 MB
    unsigned* tmp   = (unsigned*)alloc((size_t)N_EDGES * 4);
    int*      ssrc  = (int*)alloc((size_t)N_EDGES * 4);
    unsigned* g1    = (unsigned*)alloc((size_t)N_NODES * H * 4);   // 25.6 MB
    unsigned* root1 = (unsigned*)alloc((size_t)N_NODES * H * 4);   // 25.6 MB
    float2*   hB2   = (float2*)alloc((size_t)N_NODES * H * 8);     // 51.2 MB
    unsigned* g2    = (unsigned*)alloc((size_t)N_NODES * H * 4);   // 25.6 MB
    float*    y     = (float*)alloc((size_t)N_NODES * H * 4);      // 25.6 MB
    // layer-2 overlays (lifetimes disjoint from g1/root1 gather use)
    unsigned* h2u    = g1;
    unsigned* root2u = g1 + (size_t)N_NODES * C;
    unsigned* h3u    = g1 + (size_t)2 * N_NODES * C;
    float2*   h2o    = (float2*)root1;

    hipMemsetAsync(cnt, 0, (size_t)N_NODES * 4, stream);

    int nbN = (N_NODES + 255) / 256;                 // 391
    int nbH = (NBUCKETS * NBLK + 255) / 256;         // 391
    hist_kernel<<<1024, 256, 0, stream>>>(tgt, cnt);
    scan1_kernel<<<nbN, 256, 0, stream>>>(cnt, rp, bsum, N_NODES);
    scan2_kernel<<<1, 64, 0, stream>>>(bsum, nbN);
    scan3_kernel<<<(N_NODES + 1 + 255) / 256, 256, 0, stream>>>(rp, bsum, N_NODES, N_EDGES);
    dinv_kernel<<<(N_NODES + 255) / 256, 256, 0, stream>>>(cnt, dinv);

    histA_kernel<<<NBLK, 256, 0, stream>>>(tgt, hist);
    scan1_kernel<<<nbH, 256, 0, stream>>>(hist, histx, bsum, NBUCKETS * NBLK);
    scan2_kernel<<<1, 64, 0, stream>>>(bsum, nbH);
    scan3_kernel<<<nbH, 256, 0, stream>>>(histx, bsum, NBUCKETS * NBLK, -1);
    scatterC_kernel<<<NBLK, 256, 0, stream>>>(src, tgt, histx, tmp);
    bucketD_kernel<<<NBUCKETS, 256, 0, stream>>>(tmp, rp, ssrc);

    int gblocks = (N_NODES + 63) / 64;          // 1563
    int pgrid   = (N_NODES + 3) / 4;            // 25000 (wave per node)

    // ---- layer 1 (F_IN=100 -> H=64) ----
    dense1_kernel<<<gblocks, 256, 0, stream>>>(x, init_w1, root_w1, dinv, g1, root1);
    prop64_kernel<0><<<pgrid, 256, 0, stream>>>(g1, root1, b1, dinv, rp, ssrc, hB2, nullptr);
    dense_mid_kernel<<<gblocks, 256, 0, stream>>>(hB2, w1, dinv, g2);
    prop64_kernel<1><<<pgrid, 256, 0, stream>>>(g2, root1, b1, dinv, rp, ssrc, nullptr, y);

    // ---- layer 2 (H=64 -> C=18) ----
    dense_y2_kernel<<<gblocks, 256, 0, stream>>>(y, init_w2, root_w2, dinv, h2u, root2u);
    prop18_kernel<0><<<pgrid, 256, 0, stream>>>(h2u, root2u, b2, dinv, rp, ssrc, h2o, nullptr);
    dense_last_kernel<<<gblocks, 256, 0, stream>>>(h2o, w2, dinv, h3u);
    prop18_kernel<1><<<pgrid, 256, 0, stream>>>(h3u, root2u, b2, dinv, rp, ssrc, nullptr, out);
}

// Round 6
// 559.314 us; speedup vs baseline: 1.6997x; 1.1470x over previous
//
#include <hip/hip_runtime.h>
#include <hip/hip_bf16.h>
#include <math.h>

#define N_NODES 100000
#define N_EDGES 1600000
#define F_IN 100
#define H 64
#define C 18
#define BSHIFT 8
#define BSIZE 256
#define NBUCKETS ((N_NODES + BSIZE - 1) >> BSHIFT)   // 391
#define NBLK 256
#define CHUNK (N_EDGES / NBLK)                       // 6250

typedef __attribute__((ext_vector_type(8))) short v8s;   // 8 bf16 (4 VGPRs)
typedef __attribute__((ext_vector_type(4))) float v4f;   // 4 f32 acc

// ----------------- bf16x2 pack/unpack -----------------

__device__ __forceinline__ unsigned bf16_rne(float f) {
    unsigned u = __float_as_uint(f);
    return (u + 0x7FFFu + ((u >> 16) & 1u)) >> 16;
}
__device__ __forceinline__ unsigned pack_bf2(float a, float b) {
    return bf16_rne(a) | (bf16_rne(b) << 16);
}
__device__ __forceinline__ float2 unpack_bf2(unsigned u) {
    return make_float2(__uint_as_float(u << 16), __uint_as_float(u & 0xFFFF0000u));
}

// ----------------- CSR build -----------------

__global__ void hist_kernel(const int* __restrict__ tgt, int* __restrict__ cnt) {
    int i = blockIdx.x * blockDim.x + threadIdx.x;
    int stride = gridDim.x * blockDim.x;
    for (int e = i; e < N_EDGES; e += stride) atomicAdd(&cnt[tgt[e]], 1);
}

__global__ void scan1_kernel(const int* __restrict__ cnt, int* __restrict__ excl,
                             int* __restrict__ bsum, int n) {
    __shared__ int tmp[256];
    int t = threadIdx.x;
    int i = blockIdx.x * 256 + t;
    int v = (i < n) ? cnt[i] : 0;
    tmp[t] = v;
    __syncthreads();
    for (int off = 1; off < 256; off <<= 1) {
        int xv = (t >= off) ? tmp[t - off] : 0;
        __syncthreads();
        tmp[t] += xv;
        __syncthreads();
    }
    if (i < n) excl[i] = tmp[t] - v;
    if (t == 255) bsum[blockIdx.x] = tmp[255];
}

__global__ void scan2_kernel(int* bsum, int nb) {
    if (blockIdx.x == 0 && threadIdx.x == 0) {
        int run = 0;
        for (int j = 0; j < nb; ++j) { int v = bsum[j]; bsum[j] = run; run += v; }
    }
}

__global__ void scan3_kernel(int* __restrict__ arr, const int* __restrict__ bsum,
                             int n, int sent) {
    int i = blockIdx.x * 256 + threadIdx.x;
    if (i < n) arr[i] += bsum[i >> 8];
    if (i == n && sent >= 0) arr[n] = sent;
}

__global__ void dinv_kernel(const int* __restrict__ cnt, float* __restrict__ dinv) {
    int i = blockIdx.x * blockDim.x + threadIdx.x;
    if (i < N_NODES) {
        int c = cnt[i];
        dinv[i] = (c > 0) ? rsqrtf((float)c) : 0.0f;
    }
}

__global__ void __launch_bounds__(256) histA_kernel(const int* __restrict__ tgt,
                                                    int* __restrict__ hist) {
    __shared__ int h[NBUCKETS];
    int blk = blockIdx.x, t = threadIdx.x;
    for (int i = t; i < NBUCKETS; i += 256) h[i] = 0;
    __syncthreads();
    int e0 = blk * CHUNK, e1 = e0 + CHUNK;
    for (int e = e0 + t; e < e1; e += 256) atomicAdd(&h[tgt[e] >> BSHIFT], 1);
    __syncthreads();
    for (int i = t; i < NBUCKETS; i += 256) hist[i * NBLK + blk] = h[i];
}

__global__ void __launch_bounds__(256) scatterC_kernel(
        const int* __restrict__ src, const int* __restrict__ tgt,
        const int* __restrict__ histx, unsigned* __restrict__ tmp) {
    __shared__ int cur[NBUCKETS];
    int blk = blockIdx.x, t = threadIdx.x;
    for (int i = t; i < NBUCKETS; i += 256) cur[i] = histx[i * NBLK + blk];
    __syncthreads();
    int e0 = blk * CHUNK, e1 = e0 + CHUNK;
    for (int e = e0 + t; e < e1; e += 256) {
        int s = src[e], tg = tgt[e];
        int b = tg >> BSHIFT;
        int pos = atomicAdd(&cur[b], 1);
        tmp[pos] = (unsigned)s | ((unsigned)(tg & (BSIZE - 1)) << 17);
    }
}

__global__ void __launch_bounds__(256) bucketD_kernel(
        const unsigned* __restrict__ tmp, const int* __restrict__ rp,
        int* __restrict__ ssrc) {
    __shared__ int rpl[BSIZE + 1];
    __shared__ int cur[BSIZE];
    int b = blockIdx.x;
    int n_lo = b << BSHIFT;
    int n_hi = min(n_lo + BSIZE, N_NODES);
    int nn = n_hi - n_lo;
    int t = threadIdx.x;
    if (t < nn) { rpl[t] = rp[n_lo + t]; cur[t] = 0; }
    if (t == 0) rpl[nn] = rp[n_hi];
    __syncthreads();
    int e_lo = rpl[0], e_hi = rpl[nn];
    for (int e = e_lo + t; e < e_hi; e += 256) {
        unsigned p = tmp[e];
        int s = (int)(p & 0x1FFFFu);
        int tl = (int)(p >> 17);
        int pos = rpl[tl] + atomicAdd(&cur[tl], 1);
        ssrc[pos] = s;
    }
}

// ----------------- prep: bf16 conversions / transposes -----------------

// xb[n][128] bf16, K-padded with zeros
__global__ void convert_x_kernel(const float* __restrict__ x, unsigned* __restrict__ xbu) {
    int idx = blockIdx.x * 256 + threadIdx.x;   // one u32 = 2 bf16
    if (idx >= N_NODES * 64) return;
    int n = idx >> 6;
    int jp = idx & 63;
    int col = jp * 2;
    float v0 = (col < F_IN) ? x[(size_t)n * F_IN + col] : 0.f;
    float v1 = (col + 1 < F_IN) ? x[(size_t)n * F_IN + col + 1] : 0.f;
    xbu[idx] = pack_bf2(v0, v1);
}

// W1T[m][col][k]: m = isWr*2+stk; transposed, K padded 100->128
__global__ void prep_w1_kernel(const float* __restrict__ Wi, const float* __restrict__ Wr,
                               ushort* __restrict__ W1T) {
    int idx = blockIdx.x * 256 + threadIdx.x;   // 4*64*128 = 32768
    if (idx >= 4 * 64 * 128) return;
    int m  = idx >> 13;
    int nn = (idx >> 7) & 63;
    int kk = idx & 127;
    int stk = m & 1, isWr = m >> 1;
    float v = 0.f;
    if (kk < F_IN) {
        const float* W = isWr ? Wr : Wi;
        v = W[((size_t)stk * F_IN + kk) * 64 + nn];
    }
    W1T[idx] = (ushort)bf16_rne(v);
}

// WmT[stk][g][f] = w1[stk][f][g]
__global__ void prep_wmid_kernel(const float* __restrict__ w1, ushort* __restrict__ WmT) {
    int idx = blockIdx.x * 256 + threadIdx.x;   // 2*64*64 = 8192
    if (idx >= 2 * 64 * 64) return;
    int stk = idx >> 12;
    int g = (idx >> 6) & 63;
    int f = idx & 63;
    WmT[idx] = (ushort)bf16_rne(w1[((size_t)stk * 64 + f) * 64 + g]);
}

// ----------------- MFMA dense kernels -----------------
// A-frag (16x16x32): lane holds A[row=lane&15][k=(lane>>4)*8+j] -> one 16B read.
// B-frag: lane holds B[k=(lane>>4)*8+j][col=lane&15] -> W stored [col][k] gives 16B read.
// C/D: col=lane&15, row=(lane>>4)*4+reg  (m89-verified mapping).
// LDS A-tiles XOR-swizzled: granule ^= (row&7) to kill the power-of-2 row-stride conflict.

// block = 64 nodes; wave w: matrix (w<2 ? Wi : Wr), cols (w&1)*32..+31, both stacks.
__global__ void __launch_bounds__(256) dense1_mfma(
        const ushort* __restrict__ xb, const ushort* __restrict__ W1T,
        const float* __restrict__ dinv,
        unsigned* __restrict__ g, unsigned* __restrict__ root) {
    __shared__ char xs[64 * 256];   // 16KB: 64 rows x 128 bf16, swizzled
    int tid = threadIdx.x;
    int b0 = blockIdx.x * 64;
    for (int i = tid; i < 1024; i += 256) {          // 64 rows * 16 granules
        int row = i >> 4, gr = i & 15;
        int grow = b0 + row;
        uint4 v = make_uint4(0, 0, 0, 0);
        if (grow < N_NODES) v = *(const uint4*)(xb + (size_t)grow * 128 + gr * 8);
        *(uint4*)(xs + row * 256 + ((gr ^ (row & 7)) << 4)) = v;
    }
    __syncthreads();
    int lane = tid & 63;
    int w = tid >> 6;
    int q = lane >> 4, cl = lane & 15;
    int isWr = w >> 1;
    int colbase = (w & 1) * 32;
    v8s bfr[2][2][4];   // [stk][ntile][kstep], resident
    #pragma unroll
    for (int stk = 0; stk < 2; ++stk)
        #pragma unroll
        for (int nt = 0; nt < 2; ++nt)
            #pragma unroll
            for (int ks = 0; ks < 4; ++ks) {
                const ushort* p = W1T + ((size_t)(isWr * 2 + stk) * 64 + colbase + nt * 16 + cl) * 128
                                  + ks * 32 + q * 8;
                bfr[stk][nt][ks] = *(const v8s*)p;
            }
    #pragma unroll
    for (int mt = 0; mt < 4; ++mt) {
        v8s afr[4];
        #pragma unroll
        for (int ks = 0; ks < 4; ++ks) {
            int row = mt * 16 + cl;
            int gr = (ks * 4 + q) ^ (row & 7);
            afr[ks] = *(const v8s*)(xs + row * 256 + (gr << 4));
        }
        v4f acc[2][2];
        #pragma unroll
        for (int stk = 0; stk < 2; ++stk)
            #pragma unroll
            for (int nt = 0; nt < 2; ++nt) {
                v4f a = {0.f, 0.f, 0.f, 0.f};
                #pragma unroll
                for (int ks = 0; ks < 4; ++ks)
                    a = __builtin_amdgcn_mfma_f32_16x16x32_bf16(afr[ks], bfr[stk][nt][ks], a, 0, 0, 0);
                acc[stk][nt] = a;
            }
        #pragma unroll
        for (int nt = 0; nt < 2; ++nt)
            #pragma unroll
            for (int reg = 0; reg < 4; ++reg) {
                int node = b0 + mt * 16 + q * 4 + reg;
                if (node < N_NODES) {
                    int col = colbase + nt * 16 + cl;
                    if (isWr == 0) {
                        float dv = dinv[node];
                        g[(size_t)node * 64 + col] = pack_bf2(dv * acc[0][nt][reg], dv * acc[1][nt][reg]);
                    } else {
                        root[(size_t)node * 64 + col] = pack_bf2(acc[0][nt][reg], acc[1][nt][reg]);
                    }
                }
            }
    }
}

// block = 64 nodes; wave w -> 16-col slice; per-stack A (hk0/hk1), per-stack B.
__global__ void __launch_bounds__(256) dense_mid_mfma(
        const ushort* __restrict__ hk0, const ushort* __restrict__ hk1,
        const ushort* __restrict__ WmT, const float* __restrict__ dinv,
        unsigned* __restrict__ g2) {
    __shared__ char hs[2 * 64 * 128];   // 16KB: [stk][row][64 bf16], swizzled
    int tid = threadIdx.x;
    int b0 = blockIdx.x * 64;
    for (int i = tid; i < 1024; i += 256) {          // 2 tiles * 64 rows * 8 granules
        int stk = i >> 9, rem = i & 511, row = rem >> 3, gr = rem & 7;
        int grow = b0 + row;
        uint4 v = make_uint4(0, 0, 0, 0);
        const ushort* srcp = stk ? hk1 : hk0;
        if (grow < N_NODES) v = *(const uint4*)(srcp + (size_t)grow * 64 + gr * 8);
        *(uint4*)(hs + stk * 8192 + row * 128 + ((gr ^ (row & 7)) << 4)) = v;
    }
    __syncthreads();
    int lane = tid & 63;
    int w = tid >> 6;
    int q = lane >> 4, cl = lane & 15;
    v8s bfr[2][2];   // [stk][kstep]
    #pragma unroll
    for (int stk = 0; stk < 2; ++stk)
        #pragma unroll
        for (int ks = 0; ks < 2; ++ks) {
            const ushort* p = WmT + ((size_t)stk * 64 + w * 16 + cl) * 64 + ks * 32 + q * 8;
            bfr[stk][ks] = *(const v8s*)p;
        }
    #pragma unroll
    for (int mt = 0; mt < 4; ++mt) {
        v4f acc[2];
        #pragma unroll
        for (int stk = 0; stk < 2; ++stk) {
            v4f a = {0.f, 0.f, 0.f, 0.f};
            #pragma unroll
            for (int ks = 0; ks < 2; ++ks) {
                int row = mt * 16 + cl;
                int gr = (ks * 4 + q) ^ (row & 7);
                v8s af = *(const v8s*)(hs + stk * 8192 + row * 128 + (gr << 4));
                a = __builtin_amdgcn_mfma_f32_16x16x32_bf16(af, bfr[stk][ks], a, 0, 0, 0);
            }
            acc[stk] = a;
        }
        #pragma unroll
        for (int reg = 0; reg < 4; ++reg) {
            int node = b0 + mt * 16 + q * 4 + reg;
            if (node < N_NODES) {
                float dv = dinv[node];
                g2[(size_t)node * 64 + w * 16 + cl] = pack_bf2(dv * acc[0][reg], dv * acc[1][reg]);
            }
        }
    }
}

// ----------------- small dense mixes (unchanged fp32 VALU) -----------------

__global__ void __launch_bounds__(256) dense_y2_kernel(
        const float* __restrict__ y, const float* __restrict__ Wi,
        const float* __restrict__ Wr, const float* __restrict__ dinv,
        unsigned* __restrict__ h2, unsigned* __restrict__ root2) {
    __shared__ float ys[64 * H];    // 16 KB
    int tid = threadIdx.x;
    int b0 = blockIdx.x * 64;
    int valid = min(64, N_NODES - b0);
    const float4* src4 = (const float4*)(y + (size_t)b0 * H);
    float4* dst4 = (float4*)ys;
    int cnt4 = valid * (H / 4);
    for (int i = tid; i < cnt4; i += 256) dst4[i] = src4[i];
    __syncthreads();
    int lane = tid & 63;
    int n0 = (tid >> 6) * 16;
    if (b0 + n0 >= N_NODES) return;
    bool act = lane < C;
    int c = act ? lane : 0;
    float ah0[16], ah1[16], ar0[16], ar1[16];
    #pragma unroll
    for (int n = 0; n < 16; ++n) { ah0[n]=0.f; ah1[n]=0.f; ar0[n]=0.f; ar1[n]=0.f; }
    const float2* ys2 = (const float2*)ys;
    for (int fp = 0; fp < H / 2; ++fp) {
        int f = 2 * fp;
        float wi00 = Wi[f * C + c],        wi01 = Wi[(f + 1) * C + c];
        float wi10 = Wi[(H + f) * C + c],  wi11 = Wi[(H + f + 1) * C + c];
        float wr00 = Wr[f * C + c],        wr01 = Wr[(f + 1) * C + c];
        float wr10 = Wr[(H + f) * C + c],  wr11 = Wr[(H + f + 1) * C + c];
        #pragma unroll
        for (int n = 0; n < 16; ++n) {
            float2 xv = ys2[(n0 + n) * (H / 2) + fp];
            ah0[n] = fmaf(xv.x, wi00, ah0[n]); ah0[n] = fmaf(xv.y, wi01, ah0[n]);
            ah1[n] = fmaf(xv.x, wi10, ah1[n]); ah1[n] = fmaf(xv.y, wi11, ah1[n]);
            ar0[n] = fmaf(xv.x, wr00, ar0[n]); ar0[n] = fmaf(xv.y, wr01, ar0[n]);
            ar1[n] = fmaf(xv.x, wr10, ar1[n]); ar1[n] = fmaf(xv.y, wr11, ar1[n]);
        }
    }
    if (act) {
        #pragma unroll
        for (int n = 0; n < 16; ++n) {
            int gn = b0 + n0 + n;
            float dv = dinv[gn];
            h2[(size_t)gn * C + c]    = pack_bf2(dv * ah0[n], dv * ah1[n]);
            root2[(size_t)gn * C + c] = pack_bf2(ar0[n], ar1[n]);
        }
    }
}

__global__ void __launch_bounds__(256) dense_last_kernel(
        const float2* __restrict__ hin, const float* __restrict__ W,
        const float* __restrict__ dinv, unsigned* __restrict__ out) {
    __shared__ float2 hs[64 * C];   // 9.2 KB
    int tid = threadIdx.x;
    int b0 = blockIdx.x * 64;
    int valid = min(64, N_NODES - b0);
    const float4* src4 = (const float4*)(hin + (size_t)b0 * C);
    float4* dst4 = (float4*)hs;
    int cnt4 = valid * C / 2;
    for (int i = tid; i < cnt4; i += 256) dst4[i] = src4[i];
    __syncthreads();
    int lane = tid & 63;
    int n0 = (tid >> 6) * 16;
    if (b0 + n0 >= N_NODES) return;
    bool act = lane < C;
    int c = act ? lane : 0;
    float a0[16], a1[16];
    #pragma unroll
    for (int n = 0; n < 16; ++n) { a0[n] = 0.f; a1[n] = 0.f; }
    #pragma unroll
    for (int j = 0; j < C; ++j) {
        float w0 = W[j * C + c];
        float w1v = W[C * C + j * C + c];
        #pragma unroll
        for (int n = 0; n < 16; ++n) {
            float2 xv = hs[(n0 + n) * C + j];
            a0[n] = fmaf(xv.x, w0, a0[n]);
            a1[n] = fmaf(xv.y, w1v, a1[n]);
        }
    }
    if (act) {
        #pragma unroll
        for (int n = 0; n < 16; ++n) {
            int gn = b0 + n0 + n;
            float dv = dinv[gn];
            out[(size_t)gn * C + c] = pack_bf2(dv * a0[n], dv * a1[n]);
        }
    }
}

// ----------------- propagation (gather over CSR, bf16x2 stacks) -----------------

template <int FINAL>
__global__ void __launch_bounds__(256) prop64_kernel(
        const unsigned* __restrict__ g, const unsigned* __restrict__ root,
        const float* __restrict__ b, const float* __restrict__ dinv,
        const int* __restrict__ rp, const int* __restrict__ ssrc,
        ushort* __restrict__ ok0, ushort* __restrict__ ok1, float* __restrict__ outp) {
    int lane = threadIdx.x & 63;
    int wid = __builtin_amdgcn_readfirstlane((int)((blockIdx.x * 256 + threadIdx.x) >> 6));
    if (wid >= N_NODES) return;
    int e0 = rp[wid], e1 = rp[wid + 1];
    float a0 = 0.f, a1 = 0.f;
    int e = e0;
    for (; e + 4 <= e1; e += 4) {
        int s0 = ssrc[e], s1 = ssrc[e + 1], s2 = ssrc[e + 2], s3 = ssrc[e + 3];
        unsigned u0 = g[(size_t)s0 * H + lane];
        unsigned u1 = g[(size_t)s1 * H + lane];
        unsigned u2 = g[(size_t)s2 * H + lane];
        unsigned u3 = g[(size_t)s3 * H + lane];
        float2 v0 = unpack_bf2(u0), v1 = unpack_bf2(u1);
        float2 v2 = unpack_bf2(u2), v3 = unpack_bf2(u3);
        a0 += (v0.x + v1.x) + (v2.x + v3.x);
        a1 += (v0.y + v1.y) + (v2.y + v3.y);
    }
    for (; e < e1; ++e) {
        float2 v = unpack_bf2(g[(size_t)ssrc[e] * H + lane]);
        a0 += v.x; a1 += v.y;
    }
    float dv = dinv[wid];
    float2 rt = unpack_bf2(root[(size_t)wid * H + lane]);
    float o0 = fmaxf(fmaf(dv, a0, rt.x + b[lane]), 0.f);
    float o1 = fmaxf(fmaf(dv, a1, rt.y + b[H + lane]), 0.f);
    if (FINAL) {
        outp[(size_t)wid * H + lane] = 0.5f * (o0 + o1);
    } else {
        ok0[(size_t)wid * H + lane] = (ushort)bf16_rne(o0);
        ok1[(size_t)wid * H + lane] = (ushort)bf16_rne(o1);
    }
}

template <int FINAL>
__global__ void __launch_bounds__(256) prop18_kernel(
        const unsigned* __restrict__ g, const unsigned* __restrict__ root,
        const float* __restrict__ b, const float* __restrict__ dinv,
        const int* __restrict__ rp, const int* __restrict__ ssrc,
        float2* __restrict__ out2, float* __restrict__ outp) {
    int lane = threadIdx.x & 63;
    int wid = __builtin_amdgcn_readfirstlane((int)((blockIdx.x * 256 + threadIdx.x) >> 6));
    if (wid >= N_NODES) return;
    int e0 = rp[wid], e1 = rp[wid + 1];
    bool act = lane < C;
    int c = act ? lane : 0;
    float a0 = 0.f, a1 = 0.f;
    int e = e0;
    for (; e + 4 <= e1; e += 4) {
        int s0 = ssrc[e], s1 = ssrc[e + 1], s2 = ssrc[e + 2], s3 = ssrc[e + 3];
        unsigned u0 = g[(size_t)s0 * C + c];
        unsigned u1 = g[(size_t)s1 * C + c];
        unsigned u2 = g[(size_t)s2 * C + c];
        unsigned u3 = g[(size_t)s3 * C + c];
        float2 v0 = unpack_bf2(u0), v1 = unpack_bf2(u1);
        float2 v2 = unpack_bf2(u2), v3 = unpack_bf2(u3);
        if (act) {
            a0 += (v0.x + v1.x) + (v2.x + v3.x);
            a1 += (v0.y + v1.y) + (v2.y + v3.y);
        }
    }
    for (; e < e1; ++e) {
        float2 v = unpack_bf2(g[(size_t)ssrc[e] * C + c]);
        if (act) { a0 += v.x; a1 += v.y; }
    }
    float dv = dinv[wid];
    float o0 = 0.f, o1 = 0.f;
    if (act) {
        float2 rt = unpack_bf2(root[(size_t)wid * C + c]);
        o0 = fmaxf(fmaf(dv, a0, rt.x + b[c]), 0.f);
        o1 = fmaxf(fmaf(dv, a1, rt.y + b[C + c]), 0.f);
    }
    if (!FINAL) {
        if (act) out2[(size_t)wid * C + c] = make_float2(o0, o1);
    } else {
        float m = act ? 0.5f * (o0 + o1) : -INFINITY;
        float mx = m;
        #pragma unroll
        for (int off = 16; off >= 1; off >>= 1) mx = fmaxf(mx, __shfl_xor(mx, off, 64));
        float ex = act ? __expf(m - mx) : 0.f;
        float sum = ex;
        #pragma unroll
        for (int off = 16; off >= 1; off >>= 1) sum += __shfl_xor(sum, off, 64);
        if (act) outp[(size_t)wid * C + c] = m - mx - logf(sum);
    }
}

// ----------------- launch -----------------

extern "C" void kernel_launch(void* const* d_in, const int* in_sizes, int n_in,
                              void* d_out, int out_size, void* d_ws, size_t ws_size,
                              hipStream_t stream) {
    const float* x        = (const float*)d_in[0];
    const int*   ei       = (const int*)d_in[1];
    const float* init_w1  = (const float*)d_in[2];
    const float* w1       = (const float*)d_in[3];
    const float* root_w1  = (const float*)d_in[4];
    const float* b1       = (const float*)d_in[5];
    const float* init_w2  = (const float*)d_in[6];
    const float* w2       = (const float*)d_in[7];
    const float* root_w2  = (const float*)d_in[8];
    const float* b2       = (const float*)d_in[9];
    const int* src = ei;
    const int* tgt = ei + N_EDGES;
    float* out = (float*)d_out;

    char* w = (char*)d_ws;
    size_t off = 0;
    auto alloc = [&](size_t bytes) -> char* {
        char* p = w + off;
        off += (bytes + 255) & ~(size_t)255;
        return p;
    };
    int*      cnt   = (int*)alloc((size_t)N_NODES * 4);
    int*      rp    = (int*)alloc((size_t)(N_NODES + 1) * 4);
    float*    dinv  = (float*)alloc((size_t)N_NODES * 4);
    int*      bsum  = (int*)alloc(512 * 4);
    int*      hist  = (int*)alloc((size_t)NBUCKETS * NBLK * 4);
    int*      histx = (int*)alloc((size_t)NBUCKETS * NBLK * 4);
    unsigned* tmp   = (unsigned*)alloc((size_t)N_EDGES * 4);
    int*      ssrc  = (int*)alloc((size_t)N_EDGES * 4);
    ushort*   xb    = (ushort*)alloc((size_t)N_NODES * 128 * 2);  // 25.6 MB
    ushort*   W1T   = (ushort*)alloc((size_t)4 * 64 * 128 * 2);
    ushort*   WmT   = (ushort*)alloc((size_t)2 * 64 * 64 * 2);
    unsigned* g1    = (unsigned*)alloc((size_t)N_NODES * H * 4);  // 25.6 MB
    unsigned* root1 = (unsigned*)alloc((size_t)N_NODES * H * 4);  // 25.6 MB
    ushort*   hk0   = (ushort*)alloc((size_t)N_NODES * H * 2);    // 12.8 MB
    ushort*   hk1   = (ushort*)alloc((size_t)N_NODES * H * 2);    // 12.8 MB
    unsigned* g2    = (unsigned*)alloc((size_t)N_NODES * H * 4);  // 25.6 MB
    float*    y     = (float*)alloc((size_t)N_NODES * H * 4);     // 25.6 MB
    // layer-2 overlays (lifetimes disjoint)
    unsigned* h2u    = g1;
    unsigned* root2u = g1 + (size_t)N_NODES * C;
    unsigned* h3u    = g1 + (size_t)2 * N_NODES * C;
    float2*   h2o    = (float2*)root1;

    hipMemsetAsync(cnt, 0, (size_t)N_NODES * 4, stream);

    int nbN = (N_NODES + 255) / 256;                 // 391
    int nbH = (NBUCKETS * NBLK + 255) / 256;         // 391
    hist_kernel<<<1024, 256, 0, stream>>>(tgt, cnt);
    scan1_kernel<<<nbN, 256, 0, stream>>>(cnt, rp, bsum, N_NODES);
    scan2_kernel<<<1, 64, 0, stream>>>(bsum, nbN);
    scan3_kernel<<<(N_NODES + 1 + 255) / 256, 256, 0, stream>>>(rp, bsum, N_NODES, N_EDGES);
    dinv_kernel<<<(N_NODES + 255) / 256, 256, 0, stream>>>(cnt, dinv);

    histA_kernel<<<NBLK, 256, 0, stream>>>(tgt, hist);
    scan1_kernel<<<nbH, 256, 0, stream>>>(hist, histx, bsum, NBUCKETS * NBLK);
    scan2_kernel<<<1, 64, 0, stream>>>(bsum, nbH);
    scan3_kernel<<<nbH, 256, 0, stream>>>(histx, bsum, NBUCKETS * NBLK, -1);
    scatterC_kernel<<<NBLK, 256, 0, stream>>>(src, tgt, histx, tmp);
    bucketD_kernel<<<NBUCKETS, 256, 0, stream>>>(tmp, rp, ssrc);

    convert_x_kernel<<<(N_NODES * 64 + 255) / 256, 256, 0, stream>>>(x, (unsigned*)xb);
    prep_w1_kernel<<<128, 256, 0, stream>>>(init_w1, root_w1, W1T);
    prep_wmid_kernel<<<32, 256, 0, stream>>>(w1, WmT);

    int gblocks = (N_NODES + 63) / 64;          // 1563
    int pgrid   = (N_NODES + 3) / 4;            // 25000 (wave per node)

    // ---- layer 1 (F_IN=100 -> H=64) ----
    dense1_mfma<<<gblocks, 256, 0, stream>>>(xb, W1T, dinv, g1, root1);
    prop64_kernel<0><<<pgrid, 256, 0, stream>>>(g1, root1, b1, dinv, rp, ssrc, hk0, hk1, nullptr);
    dense_mid_mfma<<<gblocks, 256, 0, stream>>>(hk0, hk1, WmT, dinv, g2);
    prop64_kernel<1><<<pgrid, 256, 0, stream>>>(g2, root1, b1, dinv, rp, ssrc, nullptr, nullptr, y);

    // ---- layer 2 (H=64 -> C=18) ----
    dense_y2_kernel<<<gblocks, 256, 0, stream>>>(y, init_w2, root_w2, dinv, h2u, root2u);
    prop18_kernel<0><<<pgrid, 256, 0, stream>>>(h2u, root2u, b2, dinv, rp, ssrc, h2o, nullptr);
    dense_last_kernel<<<gblocks, 256, 0, stream>>>(h2o, w2, dinv, h3u);
    prop18_kernel<1><<<pgrid, 256, 0, stream>>>(h3u, root2u, b2, dinv, rp, ssrc, nullptr, out);
}

// Round 7
// 519.191 us; speedup vs baseline: 1.8310x; 1.0773x over previous
//
#include <hip/hip_runtime.h>
#include <hip/hip_bf16.h>
#include <math.h>

#define N_NODES 100000
#define N_EDGES 1600000
#define F_IN 100
#define H 64
#define C 18
#define BSHIFT 8
#define BSIZE 256
#define NBUCKETS ((N_NODES + BSIZE - 1) >> BSHIFT)   // 391
#define NBLK 256
#define CHUNK (N_EDGES / NBLK)                       // 6250

typedef __attribute__((ext_vector_type(8))) short v8s;   // 8 bf16 (4 VGPRs)
typedef __attribute__((ext_vector_type(4))) float v4f;   // 4 f32 acc

// ----------------- bf16x2 pack/unpack -----------------

__device__ __forceinline__ unsigned bf16_rne(float f) {
    unsigned u = __float_as_uint(f);
    return (u + 0x7FFFu + ((u >> 16) & 1u)) >> 16;
}
__device__ __forceinline__ unsigned pack_bf2(float a, float b) {
    return bf16_rne(a) | (bf16_rne(b) << 16);
}
__device__ __forceinline__ float2 unpack_bf2(unsigned u) {
    return make_float2(__uint_as_float(u << 16), __uint_as_float(u & 0xFFFF0000u));
}

// ----------------- CSR build -----------------

__global__ void hist_kernel(const int* __restrict__ tgt, int* __restrict__ cnt) {
    int i = blockIdx.x * blockDim.x + threadIdx.x;
    int stride = gridDim.x * blockDim.x;
    for (int e = i; e < N_EDGES; e += stride) atomicAdd(&cnt[tgt[e]], 1);
}

__global__ void scan1_kernel(const int* __restrict__ cnt, int* __restrict__ excl,
                             int* __restrict__ bsum, int n) {
    __shared__ int tmp[256];
    int t = threadIdx.x;
    int i = blockIdx.x * 256 + t;
    int v = (i < n) ? cnt[i] : 0;
    tmp[t] = v;
    __syncthreads();
    for (int off = 1; off < 256; off <<= 1) {
        int xv = (t >= off) ? tmp[t - off] : 0;
        __syncthreads();
        tmp[t] += xv;
        __syncthreads();
    }
    if (i < n) excl[i] = tmp[t] - v;
    if (t == 255) bsum[blockIdx.x] = tmp[255];
}

__global__ void scan2_kernel(int* bsum, int nb) {
    if (blockIdx.x == 0 && threadIdx.x == 0) {
        int run = 0;
        for (int j = 0; j < nb; ++j) { int v = bsum[j]; bsum[j] = run; run += v; }
    }
}

__global__ void scan3_kernel(int* __restrict__ arr, const int* __restrict__ bsum,
                             int n, int sent) {
    int i = blockIdx.x * 256 + threadIdx.x;
    if (i < n) arr[i] += bsum[i >> 8];
    if (i == n && sent >= 0) arr[n] = sent;
}

__global__ void dinv_kernel(const int* __restrict__ cnt, float* __restrict__ dinv) {
    int i = blockIdx.x * blockDim.x + threadIdx.x;
    if (i < N_NODES) {
        int c = cnt[i];
        dinv[i] = (c > 0) ? rsqrtf((float)c) : 0.0f;
    }
}

__global__ void __launch_bounds__(256) histA_kernel(const int* __restrict__ tgt,
                                                    int* __restrict__ hist) {
    __shared__ int h[NBUCKETS];
    int blk = blockIdx.x, t = threadIdx.x;
    for (int i = t; i < NBUCKETS; i += 256) h[i] = 0;
    __syncthreads();
    int e0 = blk * CHUNK, e1 = e0 + CHUNK;
    for (int e = e0 + t; e < e1; e += 256) atomicAdd(&h[tgt[e] >> BSHIFT], 1);
    __syncthreads();
    for (int i = t; i < NBUCKETS; i += 256) hist[i * NBLK + blk] = h[i];
}

__global__ void __launch_bounds__(256) scatterC_kernel(
        const int* __restrict__ src, const int* __restrict__ tgt,
        const int* __restrict__ histx, unsigned* __restrict__ tmp) {
    __shared__ int cur[NBUCKETS];
    int blk = blockIdx.x, t = threadIdx.x;
    for (int i = t; i < NBUCKETS; i += 256) cur[i] = histx[i * NBLK + blk];
    __syncthreads();
    int e0 = blk * CHUNK, e1 = e0 + CHUNK;
    for (int e = e0 + t; e < e1; e += 256) {
        int s = src[e], tg = tgt[e];
        int b = tg >> BSHIFT;
        int pos = atomicAdd(&cur[b], 1);
        tmp[pos] = (unsigned)s | ((unsigned)(tg & (BSIZE - 1)) << 17);
    }
}

__global__ void __launch_bounds__(256) bucketD_kernel(
        const unsigned* __restrict__ tmp, const int* __restrict__ rp,
        int* __restrict__ ssrc) {
    __shared__ int rpl[BSIZE + 1];
    __shared__ int cur[BSIZE];
    int b = blockIdx.x;
    int n_lo = b << BSHIFT;
    int n_hi = min(n_lo + BSIZE, N_NODES);
    int nn = n_hi - n_lo;
    int t = threadIdx.x;
    if (t < nn) { rpl[t] = rp[n_lo + t]; cur[t] = 0; }
    if (t == 0) rpl[nn] = rp[n_hi];
    __syncthreads();
    int e_lo = rpl[0], e_hi = rpl[nn];
    for (int e = e_lo + t; e < e_hi; e += 256) {
        unsigned p = tmp[e];
        int s = (int)(p & 0x1FFFFu);
        int tl = (int)(p >> 17);
        int pos = rpl[tl] + atomicAdd(&cur[tl], 1);
        ssrc[pos] = s;
    }
}

// ----------------- prep: bf16 conversions / transposes -----------------

__global__ void convert_x_kernel(const float* __restrict__ x, unsigned* __restrict__ xbu) {
    int idx = blockIdx.x * 256 + threadIdx.x;   // one u32 = 2 bf16
    if (idx >= N_NODES * 64) return;
    int n = idx >> 6;
    int jp = idx & 63;
    int col = jp * 2;
    float v0 = (col < F_IN) ? x[(size_t)n * F_IN + col] : 0.f;
    float v1 = (col + 1 < F_IN) ? x[(size_t)n * F_IN + col + 1] : 0.f;
    xbu[idx] = pack_bf2(v0, v1);
}

// W1T[m][col][k]: m = isWr*2+stk; transposed, K padded 100->128
__global__ void prep_w1_kernel(const float* __restrict__ Wi, const float* __restrict__ Wr,
                               ushort* __restrict__ W1T) {
    int idx = blockIdx.x * 256 + threadIdx.x;   // 4*64*128 = 32768
    if (idx >= 4 * 64 * 128) return;
    int m  = idx >> 13;
    int nn = (idx >> 7) & 63;
    int kk = idx & 127;
    int stk = m & 1, isWr = m >> 1;
    float v = 0.f;
    if (kk < F_IN) {
        const float* W = isWr ? Wr : Wi;
        v = W[((size_t)stk * F_IN + kk) * 64 + nn];
    }
    W1T[idx] = (ushort)bf16_rne(v);
}

// WmT[stk][g][f] = w1[stk][f][g]
__global__ void prep_wmid_kernel(const float* __restrict__ w1, ushort* __restrict__ WmT) {
    int idx = blockIdx.x * 256 + threadIdx.x;   // 2*64*64 = 8192
    if (idx >= 2 * 64 * 64) return;
    int stk = idx >> 12;
    int g = (idx >> 6) & 63;
    int f = idx & 63;
    WmT[idx] = (ushort)bf16_rne(w1[((size_t)stk * 64 + f) * 64 + g]);
}

// W2T[m][col pad32][k=64], m = isWr*2+stk; from [2][64][18] weight
__global__ void prep_w2_kernel(const float* __restrict__ Wi, const float* __restrict__ Wr,
                               ushort* __restrict__ W2T) {
    int idx = blockIdx.x * 256 + threadIdx.x;   // 4*32*64 = 8192
    if (idx >= 4 * 32 * 64) return;
    int m   = idx >> 11;
    int col = (idx >> 6) & 31;
    int k   = idx & 63;
    int stk = m & 1, isWr = m >> 1;
    float v = 0.f;
    if (col < C) {
        const float* W = isWr ? Wr : Wi;
        v = W[((size_t)stk * H + k) * C + col];
    }
    W2T[idx] = (ushort)bf16_rne(v);
}

// W3T[stk][col pad32][k pad32]; from w2 [2][18][18]
__global__ void prep_w3_kernel(const float* __restrict__ w2, ushort* __restrict__ W3T) {
    int idx = blockIdx.x * 256 + threadIdx.x;   // 2*32*32 = 2048
    if (idx >= 2 * 32 * 32) return;
    int stk = idx >> 10;
    int col = (idx >> 5) & 31;
    int k   = idx & 31;
    float v = 0.f;
    if (col < C && k < C) v = w2[((size_t)stk * C + k) * C + col];
    W3T[idx] = (ushort)bf16_rne(v);
}

// ----------------- MFMA dense kernels -----------------
// A-frag (16x16x32): lane holds A[row=lane&15][k=(lane>>4)*8+j] -> one 16B read.
// B-frag: lane holds B[k=(lane>>4)*8+j][col=lane&15] -> W stored [col][k] gives 16B read.
// C/D: col=lane&15, row=(lane>>4)*4+reg  (m89-verified mapping).
// LDS A-tiles XOR-swizzled: granule ^= (row&7) (or &3) kills power-of-2 row-stride conflicts.

// block = 64 nodes; wave w: matrix (w<2 ? Wi : Wr), cols (w&1)*32..+31, both stacks.
__global__ void __launch_bounds__(256) dense1_mfma(
        const ushort* __restrict__ xb, const ushort* __restrict__ W1T,
        const float* __restrict__ dinv,
        unsigned* __restrict__ g, unsigned* __restrict__ root) {
    __shared__ char xs[64 * 256];   // 16KB: 64 rows x 128 bf16, swizzled
    int tid = threadIdx.x;
    int b0 = blockIdx.x * 64;
    for (int i = tid; i < 1024; i += 256) {          // 64 rows * 16 granules
        int row = i >> 4, gr = i & 15;
        int grow = b0 + row;
        uint4 v = make_uint4(0, 0, 0, 0);
        if (grow < N_NODES) v = *(const uint4*)(xb + (size_t)grow * 128 + gr * 8);
        *(uint4*)(xs + row * 256 + ((gr ^ (row & 7)) << 4)) = v;
    }
    __syncthreads();
    int lane = tid & 63;
    int w = tid >> 6;
    int q = lane >> 4, cl = lane & 15;
    int isWr = w >> 1;
    int colbase = (w & 1) * 32;
    v8s bfr[2][2][4];   // [stk][ntile][kstep]
    #pragma unroll
    for (int stk = 0; stk < 2; ++stk)
        #pragma unroll
        for (int nt = 0; nt < 2; ++nt)
            #pragma unroll
            for (int ks = 0; ks < 4; ++ks) {
                const ushort* p = W1T + ((size_t)(isWr * 2 + stk) * 64 + colbase + nt * 16 + cl) * 128
                                  + ks * 32 + q * 8;
                bfr[stk][nt][ks] = *(const v8s*)p;
            }
    #pragma unroll
    for (int mt = 0; mt < 4; ++mt) {
        v8s afr[4];
        #pragma unroll
        for (int ks = 0; ks < 4; ++ks) {
            int row = mt * 16 + cl;
            int gr = (ks * 4 + q) ^ (row & 7);
            afr[ks] = *(const v8s*)(xs + row * 256 + (gr << 4));
        }
        v4f acc[2][2];
        #pragma unroll
        for (int stk = 0; stk < 2; ++stk)
            #pragma unroll
            for (int nt = 0; nt < 2; ++nt) {
                v4f a = {0.f, 0.f, 0.f, 0.f};
                #pragma unroll
                for (int ks = 0; ks < 4; ++ks)
                    a = __builtin_amdgcn_mfma_f32_16x16x32_bf16(afr[ks], bfr[stk][nt][ks], a, 0, 0, 0);
                acc[stk][nt] = a;
            }
        #pragma unroll
        for (int nt = 0; nt < 2; ++nt)
            #pragma unroll
            for (int reg = 0; reg < 4; ++reg) {
                int node = b0 + mt * 16 + q * 4 + reg;
                if (node < N_NODES) {
                    int col = colbase + nt * 16 + cl;
                    if (isWr == 0) {
                        float dv = dinv[node];
                        g[(size_t)node * 64 + col] = pack_bf2(dv * acc[0][nt][reg], dv * acc[1][nt][reg]);
                    } else {
                        root[(size_t)node * 64 + col] = pack_bf2(acc[0][nt][reg], acc[1][nt][reg]);
                    }
                }
            }
    }
}

// block = 64 nodes; wave w -> 16-col slice; per-stack A (hk0/hk1), per-stack B.
__global__ void __launch_bounds__(256) dense_mid_mfma(
        const ushort* __restrict__ hk0, const ushort* __restrict__ hk1,
        const ushort* __restrict__ WmT, const float* __restrict__ dinv,
        unsigned* __restrict__ g2) {
    __shared__ char hs[2 * 64 * 128];   // 16KB: [stk][row][64 bf16], swizzled
    int tid = threadIdx.x;
    int b0 = blockIdx.x * 64;
    for (int i = tid; i < 1024; i += 256) {          // 2 tiles * 64 rows * 8 granules
        int stk = i >> 9, rem = i & 511, row = rem >> 3, gr = rem & 7;
        int grow = b0 + row;
        uint4 v = make_uint4(0, 0, 0, 0);
        const ushort* srcp = stk ? hk1 : hk0;
        if (grow < N_NODES) v = *(const uint4*)(srcp + (size_t)grow * 64 + gr * 8);
        *(uint4*)(hs + stk * 8192 + row * 128 + ((gr ^ (row & 7)) << 4)) = v;
    }
    __syncthreads();
    int lane = tid & 63;
    int w = tid >> 6;
    int q = lane >> 4, cl = lane & 15;
    v8s bfr[2][2];   // [stk][kstep]
    #pragma unroll
    for (int stk = 0; stk < 2; ++stk)
        #pragma unroll
        for (int ks = 0; ks < 2; ++ks) {
            const ushort* p = WmT + ((size_t)stk * 64 + w * 16 + cl) * 64 + ks * 32 + q * 8;
            bfr[stk][ks] = *(const v8s*)p;
        }
    #pragma unroll
    for (int mt = 0; mt < 4; ++mt) {
        v4f acc[2];
        #pragma unroll
        for (int stk = 0; stk < 2; ++stk) {
            v4f a = {0.f, 0.f, 0.f, 0.f};
            #pragma unroll
            for (int ks = 0; ks < 2; ++ks) {
                int row = mt * 16 + cl;
                int gr = (ks * 4 + q) ^ (row & 7);
                v8s af = *(const v8s*)(hs + stk * 8192 + row * 128 + (gr << 4));
                a = __builtin_amdgcn_mfma_f32_16x16x32_bf16(af, bfr[stk][ks], a, 0, 0, 0);
            }
            acc[stk] = a;
        }
        #pragma unroll
        for (int reg = 0; reg < 4; ++reg) {
            int node = b0 + mt * 16 + q * 4 + reg;
            if (node < N_NODES) {
                float dv = dinv[node];
                g2[(size_t)node * 64 + w * 16 + cl] = pack_bf2(dv * acc[0][reg], dv * acc[1][reg]);
            }
        }
    }
}

// block = 64 nodes; wave w: matrix (w>>1 ? Wr : Wi), node-half (w&1), both stacks.
// A = yb [N][64] bf16; B = W2T [m][32][64]. Outputs h2 (x dinv) / root2, packed (k0,k1).
__global__ void __launch_bounds__(256) dense_y2_mfma(
        const ushort* __restrict__ yb, const ushort* __restrict__ W2T,
        const float* __restrict__ dinv,
        unsigned* __restrict__ h2, unsigned* __restrict__ root2) {
    __shared__ char ys[64 * 128];   // 8KB: 64 rows x 64 bf16, swizzled
    int tid = threadIdx.x;
    int b0 = blockIdx.x * 64;
    for (int i = tid; i < 512; i += 256) {           // 64 rows * 8 granules
        int row = i >> 3, gr = i & 7;
        int grow = b0 + row;
        uint4 v = make_uint4(0, 0, 0, 0);
        if (grow < N_NODES) v = *(const uint4*)(yb + (size_t)grow * 64 + gr * 8);
        *(uint4*)(ys + row * 128 + ((gr ^ (row & 7)) << 4)) = v;
    }
    __syncthreads();
    int lane = tid & 63;
    int w = tid >> 6;
    int q = lane >> 4, cl = lane & 15;
    int isWr = w >> 1;
    int mbase = (w & 1) * 2;
    v8s bfr[2][2][2];   // [stk][ntile][kstep]
    #pragma unroll
    for (int stk = 0; stk < 2; ++stk)
        #pragma unroll
        for (int nt = 0; nt < 2; ++nt)
            #pragma unroll
            for (int ks = 0; ks < 2; ++ks) {
                const ushort* p = W2T + ((size_t)(isWr * 2 + stk) * 32 + nt * 16 + cl) * 64
                                  + ks * 32 + q * 8;
                bfr[stk][nt][ks] = *(const v8s*)p;
            }
    #pragma unroll
    for (int mi = 0; mi < 2; ++mi) {
        int mt = mbase + mi;
        v8s afr[2];
        #pragma unroll
        for (int ks = 0; ks < 2; ++ks) {
            int row = mt * 16 + cl;
            int gr = (ks * 4 + q) ^ (row & 7);
            afr[ks] = *(const v8s*)(ys + row * 128 + (gr << 4));
        }
        v4f acc[2][2];
        #pragma unroll
        for (int stk = 0; stk < 2; ++stk)
            #pragma unroll
            for (int nt = 0; nt < 2; ++nt) {
                v4f a = {0.f, 0.f, 0.f, 0.f};
                #pragma unroll
                for (int ks = 0; ks < 2; ++ks)
                    a = __builtin_amdgcn_mfma_f32_16x16x32_bf16(afr[ks], bfr[stk][nt][ks], a, 0, 0, 0);
                acc[stk][nt] = a;
            }
        #pragma unroll
        for (int nt = 0; nt < 2; ++nt)
            #pragma unroll
            for (int reg = 0; reg < 4; ++reg) {
                int node = b0 + mt * 16 + q * 4 + reg;
                int col = nt * 16 + cl;
                if (node < N_NODES && col < C) {
                    if (isWr == 0) {
                        float dv = dinv[node];
                        h2[(size_t)node * C + col] = pack_bf2(dv * acc[0][nt][reg], dv * acc[1][nt][reg]);
                    } else {
                        root2[(size_t)node * C + col] = pack_bf2(acc[0][nt][reg], acc[1][nt][reg]);
                    }
                }
            }
    }
}

// block = 64 nodes; wave w -> m-tile w; K=18 pad 32 (1 kstep); both stacks, 2 n-tiles.
__global__ void __launch_bounds__(256) dense_last_mfma(
        const ushort* __restrict__ ok0, const ushort* __restrict__ ok1,
        const ushort* __restrict__ W3T, const float* __restrict__ dinv,
        unsigned* __restrict__ h3) {
    __shared__ char hs[2 * 64 * 64];   // 8KB: [stk][row][32 bf16], swizzled (gr ^ row&3)
    int tid = threadIdx.x;
    int b0 = blockIdx.x * 64;
    for (int i = tid; i < 2048; i += 256) ((unsigned*)hs)[i] = 0;
    __syncthreads();
    for (int i = tid; i < 4096; i += 256) {          // 2 stk * 64 rows * 32 cols
        int stk = i >> 11, row = (i >> 5) & 63, col = i & 31;
        int node = b0 + row;
        if (col < C && node < N_NODES) {
            ushort v = (stk ? ok1 : ok0)[(size_t)node * C + col];
            int gr = (col >> 3) ^ (row & 3);
            *(ushort*)(hs + stk * 4096 + row * 64 + (gr << 4) + (col & 7) * 2) = v;
        }
    }
    __syncthreads();
    int lane = tid & 63;
    int w = tid >> 6;
    int q = lane >> 4, cl = lane & 15;
    v8s bfr[2][2];   // [stk][ntile]
    #pragma unroll
    for (int stk = 0; stk < 2; ++stk)
        #pragma unroll
        for (int nt = 0; nt < 2; ++nt) {
            const ushort* p = W3T + ((size_t)stk * 32 + nt * 16 + cl) * 32 + q * 8;
            bfr[stk][nt] = *(const v8s*)p;
        }
    int row = w * 16 + cl;
    int gr = q ^ (row & 3);
    v8s af0 = *(const v8s*)(hs + row * 64 + (gr << 4));
    v8s af1 = *(const v8s*)(hs + 4096 + row * 64 + (gr << 4));
    v4f acc[2][2];
    #pragma unroll
    for (int nt = 0; nt < 2; ++nt) {
        acc[0][nt] = __builtin_amdgcn_mfma_f32_16x16x32_bf16(af0, bfr[0][nt], (v4f){0.f,0.f,0.f,0.f}, 0, 0, 0);
        acc[1][nt] = __builtin_amdgcn_mfma_f32_16x16x32_bf16(af1, bfr[1][nt], (v4f){0.f,0.f,0.f,0.f}, 0, 0, 0);
    }
    #pragma unroll
    for (int nt = 0; nt < 2; ++nt)
        #pragma unroll
        for (int reg = 0; reg < 4; ++reg) {
            int node = b0 + w * 16 + q * 4 + reg;
            int col = nt * 16 + cl;
            if (node < N_NODES && col < C) {
                float dv = dinv[node];
                h3[(size_t)node * C + col] = pack_bf2(dv * acc[0][nt][reg], dv * acc[1][nt][reg]);
            }
        }
}

// ----------------- propagation (gather over CSR, bf16x2 stacks) -----------------

template <int FINAL>
__global__ void __launch_bounds__(256) prop64_kernel(
        const unsigned* __restrict__ g, const unsigned* __restrict__ root,
        const float* __restrict__ b, const float* __restrict__ dinv,
        const int* __restrict__ rp, const int* __restrict__ ssrc,
        ushort* __restrict__ ok0, ushort* __restrict__ ok1, ushort* __restrict__ yb) {
    int lane = threadIdx.x & 63;
    int wid = __builtin_amdgcn_readfirstlane((int)((blockIdx.x * 256 + threadIdx.x) >> 6));
    if (wid >= N_NODES) return;
    int e0 = rp[wid], e1 = rp[wid + 1];
    float a0 = 0.f, a1 = 0.f;
    int e = e0;
    for (; e + 4 <= e1; e += 4) {
        int s0 = ssrc[e], s1 = ssrc[e + 1], s2 = ssrc[e + 2], s3 = ssrc[e + 3];
        unsigned u0 = g[(size_t)s0 * H + lane];
        unsigned u1 = g[(size_t)s1 * H + lane];
        unsigned u2 = g[(size_t)s2 * H + lane];
        unsigned u3 = g[(size_t)s3 * H + lane];
        float2 v0 = unpack_bf2(u0), v1 = unpack_bf2(u1);
        float2 v2 = unpack_bf2(u2), v3 = unpack_bf2(u3);
        a0 += (v0.x + v1.x) + (v2.x + v3.x);
        a1 += (v0.y + v1.y) + (v2.y + v3.y);
    }
    for (; e < e1; ++e) {
        float2 v = unpack_bf2(g[(size_t)ssrc[e] * H + lane]);
        a0 += v.x; a1 += v.y;
    }
    float dv = dinv[wid];
    float2 rt = unpack_bf2(root[(size_t)wid * H + lane]);
    float o0 = fmaxf(fmaf(dv, a0, rt.x + b[lane]), 0.f);
    float o1 = fmaxf(fmaf(dv, a1, rt.y + b[H + lane]), 0.f);
    if (FINAL) {
        yb[(size_t)wid * H + lane] = (ushort)bf16_rne(0.5f * (o0 + o1));
    } else {
        ok0[(size_t)wid * H + lane] = (ushort)bf16_rne(o0);
        ok1[(size_t)wid * H + lane] = (ushort)bf16_rne(o1);
    }
}

template <int FINAL>
__global__ void __launch_bounds__(256) prop18_kernel(
        const unsigned* __restrict__ g, const unsigned* __restrict__ root,
        const float* __restrict__ b, const float* __restrict__ dinv,
        const int* __restrict__ rp, const int* __restrict__ ssrc,
        ushort* __restrict__ ok0, ushort* __restrict__ ok1, float* __restrict__ outp) {
    int lane = threadIdx.x & 63;
    int wid = __builtin_amdgcn_readfirstlane((int)((blockIdx.x * 256 + threadIdx.x) >> 6));
    if (wid >= N_NODES) return;
    int e0 = rp[wid], e1 = rp[wid + 1];
    bool act = lane < C;
    int c = act ? lane : 0;
    float a0 = 0.f, a1 = 0.f;
    int e = e0;
    for (; e + 4 <= e1; e += 4) {
        int s0 = ssrc[e], s1 = ssrc[e + 1], s2 = ssrc[e + 2], s3 = ssrc[e + 3];
        unsigned u0 = g[(size_t)s0 * C + c];
        unsigned u1 = g[(size_t)s1 * C + c];
        unsigned u2 = g[(size_t)s2 * C + c];
        unsigned u3 = g[(size_t)s3 * C + c];
        float2 v0 = unpack_bf2(u0), v1 = unpack_bf2(u1);
        float2 v2 = unpack_bf2(u2), v3 = unpack_bf2(u3);
        if (act) {
            a0 += (v0.x + v1.x) + (v2.x + v3.x);
            a1 += (v0.y + v1.y) + (v2.y + v3.y);
        }
    }
    for (; e < e1; ++e) {
        float2 v = unpack_bf2(g[(size_t)ssrc[e] * C + c]);
        if (act) { a0 += v.x; a1 += v.y; }
    }
    float dv = dinv[wid];
    float o0 = 0.f, o1 = 0.f;
    if (act) {
        float2 rt = unpack_bf2(root[(size_t)wid * C + c]);
        o0 = fmaxf(fmaf(dv, a0, rt.x + b[c]), 0.f);
        o1 = fmaxf(fmaf(dv, a1, rt.y + b[C + c]), 0.f);
    }
    if (!FINAL) {
        if (act) {
            ok0[(size_t)wid * C + c] = (ushort)bf16_rne(o0);
            ok1[(size_t)wid * C + c] = (ushort)bf16_rne(o1);
        }
    } else {
        float m = act ? 0.5f * (o0 + o1) : -INFINITY;
        float mx = m;
        #pragma unroll
        for (int off = 16; off >= 1; off >>= 1) mx = fmaxf(mx, __shfl_xor(mx, off, 64));
        float ex = act ? __expf(m - mx) : 0.f;
        float sum = ex;
        #pragma unroll
        for (int off = 16; off >= 1; off >>= 1) sum += __shfl_xor(sum, off, 64);
        if (act) outp[(size_t)wid * C + c] = m - mx - logf(sum);
    }
}

// ----------------- launch -----------------

extern "C" void kernel_launch(void* const* d_in, const int* in_sizes, int n_in,
                              void* d_out, int out_size, void* d_ws, size_t ws_size,
                              hipStream_t stream) {
    const float* x        = (const float*)d_in[0];
    const int*   ei       = (const int*)d_in[1];
    const float* init_w1  = (const float*)d_in[2];
    const float* w1       = (const float*)d_in[3];
    const float* root_w1  = (const float*)d_in[4];
    const float* b1       = (const float*)d_in[5];
    const float* init_w2  = (const float*)d_in[6];
    const float* w2       = (const float*)d_in[7];
    const float* root_w2  = (const float*)d_in[8];
    const float* b2       = (const float*)d_in[9];
    const int* src = ei;
    const int* tgt = ei + N_EDGES;
    float* out = (float*)d_out;

    char* w = (char*)d_ws;
    size_t off = 0;
    auto alloc = [&](size_t bytes) -> char* {
        char* p = w + off;
        off += (bytes + 255) & ~(size_t)255;
        return p;
    };
    int*      cnt   = (int*)alloc((size_t)N_NODES * 4);
    int*      rp    = (int*)alloc((size_t)(N_NODES + 1) * 4);
    float*    dinv  = (float*)alloc((size_t)N_NODES * 4);
    int*      bsum  = (int*)alloc(512 * 4);
    int*      hist  = (int*)alloc((size_t)NBUCKETS * NBLK * 4);
    int*      histx = (int*)alloc((size_t)NBUCKETS * NBLK * 4);
    unsigned* tmp   = (unsigned*)alloc((size_t)N_EDGES * 4);
    int*      ssrc  = (int*)alloc((size_t)N_EDGES * 4);
    ushort*   xb    = (ushort*)alloc((size_t)N_NODES * 128 * 2);  // 25.6 MB
    ushort*   W1T   = (ushort*)alloc((size_t)4 * 64 * 128 * 2);
    ushort*   WmT   = (ushort*)alloc((size_t)2 * 64 * 64 * 2);
    ushort*   W2T   = (ushort*)alloc((size_t)4 * 32 * 64 * 2);
    ushort*   W3T   = (ushort*)alloc((size_t)2 * 32 * 32 * 2);
    unsigned* g1    = (unsigned*)alloc((size_t)N_NODES * H * 4);  // 25.6 MB
    unsigned* root1 = (unsigned*)alloc((size_t)N_NODES * H * 4);  // 25.6 MB
    ushort*   hk0   = (ushort*)alloc((size_t)N_NODES * H * 2);    // 12.8 MB
    ushort*   hk1   = (ushort*)alloc((size_t)N_NODES * H * 2);    // 12.8 MB
    unsigned* g2    = (unsigned*)alloc((size_t)N_NODES * H * 4);  // 25.6 MB
    ushort*   yb    = (ushort*)alloc((size_t)N_NODES * H * 2);    // 12.8 MB
    // layer-2 overlays (lifetimes disjoint)
    unsigned* h2u    = g1;                                   // [N*C] u32
    unsigned* root2u = g1 + (size_t)N_NODES * C;             // [N*C] u32
    unsigned* h3u    = g1 + (size_t)2 * N_NODES * C;         // [N*C] u32
    ushort*   p18k0  = (ushort*)root1;                       // [N*C] bf16
    ushort*   p18k1  = (ushort*)root1 + (size_t)N_NODES * C; // [N*C] bf16

    hipMemsetAsync(cnt, 0, (size_t)N_NODES * 4, stream);

    int nbN = (N_NODES + 255) / 256;                 // 391
    int nbH = (NBUCKETS * NBLK + 255) / 256;         // 391
    hist_kernel<<<1024, 256, 0, stream>>>(tgt, cnt);
    scan1_kernel<<<nbN, 256, 0, stream>>>(cnt, rp, bsum, N_NODES);
    scan2_kernel<<<1, 64, 0, stream>>>(bsum, nbN);
    scan3_kernel<<<(N_NODES + 1 + 255) / 256, 256, 0, stream>>>(rp, bsum, N_NODES, N_EDGES);
    dinv_kernel<<<(N_NODES + 255) / 256, 256, 0, stream>>>(cnt, dinv);

    histA_kernel<<<NBLK, 256, 0, stream>>>(tgt, hist);
    scan1_kernel<<<nbH, 256, 0, stream>>>(hist, histx, bsum, NBUCKETS * NBLK);
    scan2_kernel<<<1, 64, 0, stream>>>(bsum, nbH);
    scan3_kernel<<<nbH, 256, 0, stream>>>(histx, bsum, NBUCKETS * NBLK, -1);
    scatterC_kernel<<<NBLK, 256, 0, stream>>>(src, tgt, histx, tmp);
    bucketD_kernel<<<NBUCKETS, 256, 0, stream>>>(tmp, rp, ssrc);

    convert_x_kernel<<<(N_NODES * 64 + 255) / 256, 256, 0, stream>>>(x, (unsigned*)xb);
    prep_w1_kernel<<<128, 256, 0, stream>>>(init_w1, root_w1, W1T);
    prep_wmid_kernel<<<32, 256, 0, stream>>>(w1, WmT);
    prep_w2_kernel<<<32, 256, 0, stream>>>(init_w2, root_w2, W2T);
    prep_w3_kernel<<<8, 256, 0, stream>>>(w2, W3T);

    int gblocks = (N_NODES + 63) / 64;          // 1563
    int pgrid   = (N_NODES + 3) / 4;            // 25000 (wave per node)

    // ---- layer 1 (F_IN=100 -> H=64) ----
    dense1_mfma<<<gblocks, 256, 0, stream>>>(xb, W1T, dinv, g1, root1);
    prop64_kernel<0><<<pgrid, 256, 0, stream>>>(g1, root1, b1, dinv, rp, ssrc, hk0, hk1, nullptr);
    dense_mid_mfma<<<gblocks, 256, 0, stream>>>(hk0, hk1, WmT, dinv, g2);
    prop64_kernel<1><<<pgrid, 256, 0, stream>>>(g2, root1, b1, dinv, rp, ssrc, nullptr, nullptr, yb);

    // ---- layer 2 (H=64 -> C=18) ----
    dense_y2_mfma<<<gblocks, 256, 0, stream>>>(yb, W2T, dinv, h2u, root2u);
    prop18_kernel<0><<<pgrid, 256, 0, stream>>>(h2u, root2u, b2, dinv, rp, ssrc, p18k0, p18k1, nullptr);
    dense_last_mfma<<<gblocks, 256, 0, stream>>>(p18k0, p18k1, W3T, dinv, h3u);
    prop18_kernel<1><<<pgrid, 256, 0, stream>>>(h3u, root2u, b2, dinv, rp, ssrc, nullptr, nullptr, out);
}

// Round 8
// 406.029 us; speedup vs baseline: 2.3413x; 1.2787x over previous
//
#include <hip/hip_runtime.h>
#include <hip/hip_bf16.h>
#include <math.h>

#define N_NODES 100000
#define N_EDGES 1600000
#define F_IN 100
#define H 64
#define C 18
#define BSHIFT 8
#define BSIZE 256
#define NBUCKETS ((N_NODES + BSIZE - 1) >> BSHIFT)   // 391
#define NBLK 256
#define CHUNK (N_EDGES / NBLK)                       // 6250

typedef __attribute__((ext_vector_type(8))) short v8s;   // 8 bf16 (4 VGPRs)
typedef __attribute__((ext_vector_type(4))) float v4f;   // 4 f32 acc

// ----------------- bf16x2 pack/unpack -----------------

__device__ __forceinline__ unsigned bf16_rne(float f) {
    unsigned u = __float_as_uint(f);
    return (u + 0x7FFFu + ((u >> 16) & 1u)) >> 16;
}
__device__ __forceinline__ unsigned pack_bf2(float a, float b) {
    return bf16_rne(a) | (bf16_rne(b) << 16);
}
__device__ __forceinline__ float2 unpack_bf2(unsigned u) {
    return make_float2(__uint_as_float(u << 16), __uint_as_float(u & 0xFFFF0000u));
}

// ----------------- scan helpers (for histx only) -----------------

__global__ void scan1_kernel(const int* __restrict__ cnt, int* __restrict__ excl,
                             int* __restrict__ bsum, int n) {
    __shared__ int tmp[256];
    int t = threadIdx.x;
    int i = blockIdx.x * 256 + t;
    int v = (i < n) ? cnt[i] : 0;
    tmp[t] = v;
    __syncthreads();
    for (int off = 1; off < 256; off <<= 1) {
        int xv = (t >= off) ? tmp[t - off] : 0;
        __syncthreads();
        tmp[t] += xv;
        __syncthreads();
    }
    if (i < n) excl[i] = tmp[t] - v;
    if (t == 255) bsum[blockIdx.x] = tmp[255];
}

__global__ void scan2_kernel(int* bsum, int nb) {
    if (blockIdx.x == 0 && threadIdx.x == 0) {
        int run = 0;
        for (int j = 0; j < nb; ++j) { int v = bsum[j]; bsum[j] = run; run += v; }
    }
}

__global__ void scan3_kernel(int* __restrict__ arr, const int* __restrict__ bsum,
                             int n, int sent) {
    int i = blockIdx.x * 256 + threadIdx.x;
    if (i < n) arr[i] += bsum[i >> 8];
    if (i == n && sent >= 0) arr[n] = sent;
}

// ----------------- bucket sort (no global atomics anywhere) -----------------

// Pass A: per-(bucket, block) histogram via LDS.
__global__ void __launch_bounds__(256) histA_kernel(const int* __restrict__ tgt,
                                                    int* __restrict__ hist) {
    __shared__ int h[NBUCKETS];
    int blk = blockIdx.x, t = threadIdx.x;
    for (int i = t; i < NBUCKETS; i += 256) h[i] = 0;
    __syncthreads();
    int e0 = blk * CHUNK, e1 = e0 + CHUNK;
    for (int e = e0 + t; e < e1; e += 256) atomicAdd(&h[tgt[e] >> BSHIFT], 1);
    __syncthreads();
    for (int i = t; i < NBUCKETS; i += 256) hist[i * NBLK + blk] = h[i];
}

// Pass C: scatter edges to exact bucket positions (LDS cursors).
// packed word = src | (t_local << 17)   (src < 2^17, t_local < 256)
__global__ void __launch_bounds__(256) scatterC_kernel(
        const int* __restrict__ src, const int* __restrict__ tgt,
        const int* __restrict__ histx, unsigned* __restrict__ tmp) {
    __shared__ int cur[NBUCKETS];
    int blk = blockIdx.x, t = threadIdx.x;
    for (int i = t; i < NBUCKETS; i += 256) cur[i] = histx[i * NBLK + blk];
    __syncthreads();
    int e0 = blk * CHUNK, e1 = e0 + CHUNK;
    for (int e = e0 + t; e < e1; e += 256) {
        int s = src[e], tg = tgt[e];
        int b = tg >> BSHIFT;
        int pos = atomicAdd(&cur[b], 1);
        tmp[pos] = (unsigned)s | ((unsigned)(tg & (BSIZE - 1)) << 17);
    }
}

// Pass D2: one block per bucket. LDS histogram of t_local -> per-node degree;
// LDS scan -> per-node CSR offsets; writes rp, dinv, and node-sorted ssrc.
// Replaces the old global-atomic hist_kernel + N-scan + dinv + bucketD.
__global__ void __launch_bounds__(256) bucketD2_kernel(
        const unsigned* __restrict__ tmp, const int* __restrict__ histx,
        int* __restrict__ rp, float* __restrict__ dinv, int* __restrict__ ssrc) {
    __shared__ int cnt_l[BSIZE];
    __shared__ int scan_l[BSIZE];
    int b = blockIdx.x;
    int t = threadIdx.x;
    int e_lo = histx[(size_t)b * NBLK];
    int e_hi = (b + 1 < NBUCKETS) ? histx[(size_t)(b + 1) * NBLK] : N_EDGES;
    int n_lo = b << BSHIFT;
    int n_hi = min(n_lo + BSIZE, N_NODES);
    int nn = n_hi - n_lo;
    cnt_l[t] = 0;
    __syncthreads();
    for (int e = e_lo + t; e < e_hi; e += 256)
        atomicAdd(&cnt_l[(int)(tmp[e] >> 17)], 1);
    __syncthreads();
    int v = cnt_l[t];
    scan_l[t] = v;
    __syncthreads();
    for (int off = 1; off < 256; off <<= 1) {
        int xv = (t >= off) ? scan_l[t - off] : 0;
        __syncthreads();
        scan_l[t] += xv;
        __syncthreads();
    }
    int my_start = e_lo + scan_l[t] - v;   // exclusive scan + bucket base
    if (t < nn) {
        rp[n_lo + t] = my_start;
        dinv[n_lo + t] = (v > 0) ? rsqrtf((float)v) : 0.f;
    }
    if (b == NBUCKETS - 1 && t == 0) rp[N_NODES] = N_EDGES;
    __syncthreads();
    cnt_l[t] = my_start;   // reuse as cursor
    __syncthreads();
    for (int e = e_lo + t; e < e_hi; e += 256) {
        unsigned p = tmp[e];
        int s = (int)(p & 0x1FFFFu);
        int tl = (int)(p >> 17);
        int pos = atomicAdd(&cnt_l[tl], 1);
        ssrc[pos] = s;
    }
}

// ----------------- prep: bf16 conversions / transposes -----------------

__global__ void convert_x_kernel(const float* __restrict__ x, unsigned* __restrict__ xbu) {
    int idx = blockIdx.x * 256 + threadIdx.x;   // one u32 = 2 bf16
    if (idx >= N_NODES * 64) return;
    int n = idx >> 6;
    int jp = idx & 63;
    int col = jp * 2;
    float v0 = (col < F_IN) ? x[(size_t)n * F_IN + col] : 0.f;
    float v1 = (col + 1 < F_IN) ? x[(size_t)n * F_IN + col + 1] : 0.f;
    xbu[idx] = pack_bf2(v0, v1);
}

// W1T[m][col][k]: m = isWr*2+stk; transposed, K padded 100->128
__global__ void prep_w1_kernel(const float* __restrict__ Wi, const float* __restrict__ Wr,
                               ushort* __restrict__ W1T) {
    int idx = blockIdx.x * 256 + threadIdx.x;   // 4*64*128 = 32768
    if (idx >= 4 * 64 * 128) return;
    int m  = idx >> 13;
    int nn = (idx >> 7) & 63;
    int kk = idx & 127;
    int stk = m & 1, isWr = m >> 1;
    float v = 0.f;
    if (kk < F_IN) {
        const float* W = isWr ? Wr : Wi;
        v = W[((size_t)stk * F_IN + kk) * 64 + nn];
    }
    W1T[idx] = (ushort)bf16_rne(v);
}

// WmT[stk][g][f] = w1[stk][f][g]
__global__ void prep_wmid_kernel(const float* __restrict__ w1, ushort* __restrict__ WmT) {
    int idx = blockIdx.x * 256 + threadIdx.x;   // 2*64*64 = 8192
    if (idx >= 2 * 64 * 64) return;
    int stk = idx >> 12;
    int g = (idx >> 6) & 63;
    int f = idx & 63;
    WmT[idx] = (ushort)bf16_rne(w1[((size_t)stk * 64 + f) * 64 + g]);
}

// W2T[m][col pad32][k=64], m = isWr*2+stk; from [2][64][18] weight
__global__ void prep_w2_kernel(const float* __restrict__ Wi, const float* __restrict__ Wr,
                               ushort* __restrict__ W2T) {
    int idx = blockIdx.x * 256 + threadIdx.x;   // 4*32*64 = 8192
    if (idx >= 4 * 32 * 64) return;
    int m   = idx >> 11;
    int col = (idx >> 6) & 31;
    int k   = idx & 63;
    int stk = m & 1, isWr = m >> 1;
    float v = 0.f;
    if (col < C) {
        const float* W = isWr ? Wr : Wi;
        v = W[((size_t)stk * H + k) * C + col];
    }
    W2T[idx] = (ushort)bf16_rne(v);
}

// W3T[stk][col pad32][k pad32]; from w2 [2][18][18]
__global__ void prep_w3_kernel(const float* __restrict__ w2, ushort* __restrict__ W3T) {
    int idx = blockIdx.x * 256 + threadIdx.x;   // 2*32*32 = 2048
    if (idx >= 2 * 32 * 32) return;
    int stk = idx >> 10;
    int col = (idx >> 5) & 31;
    int k   = idx & 31;
    float v = 0.f;
    if (col < C && k < C) v = w2[((size_t)stk * C + k) * C + col];
    W3T[idx] = (ushort)bf16_rne(v);
}

// ----------------- MFMA dense kernels -----------------
// A-frag (16x16x32): lane holds A[row=lane&15][k=(lane>>4)*8+j] -> one 16B read.
// B-frag: lane holds B[k=(lane>>4)*8+j][col=lane&15] -> W stored [col][k] gives 16B read.
// C/D: col=lane&15, row=(lane>>4)*4+reg  (m89-verified mapping).
// LDS A-tiles XOR-swizzled: granule ^= (row&7) (or &3) kills power-of-2 row-stride conflicts.

// block = 64 nodes; wave w: matrix (w<2 ? Wi : Wr), cols (w&1)*32..+31, both stacks.
__global__ void __launch_bounds__(256) dense1_mfma(
        const ushort* __restrict__ xb, const ushort* __restrict__ W1T,
        const float* __restrict__ dinv,
        unsigned* __restrict__ g, unsigned* __restrict__ root) {
    __shared__ char xs[64 * 256];   // 16KB: 64 rows x 128 bf16, swizzled
    int tid = threadIdx.x;
    int b0 = blockIdx.x * 64;
    for (int i = tid; i < 1024; i += 256) {          // 64 rows * 16 granules
        int row = i >> 4, gr = i & 15;
        int grow = b0 + row;
        uint4 v = make_uint4(0, 0, 0, 0);
        if (grow < N_NODES) v = *(const uint4*)(xb + (size_t)grow * 128 + gr * 8);
        *(uint4*)(xs + row * 256 + ((gr ^ (row & 7)) << 4)) = v;
    }
    __syncthreads();
    int lane = tid & 63;
    int w = tid >> 6;
    int q = lane >> 4, cl = lane & 15;
    int isWr = w >> 1;
    int colbase = (w & 1) * 32;
    v8s bfr[2][2][4];   // [stk][ntile][kstep]
    #pragma unroll
    for (int stk = 0; stk < 2; ++stk)
        #pragma unroll
        for (int nt = 0; nt < 2; ++nt)
            #pragma unroll
            for (int ks = 0; ks < 4; ++ks) {
                const ushort* p = W1T + ((size_t)(isWr * 2 + stk) * 64 + colbase + nt * 16 + cl) * 128
                                  + ks * 32 + q * 8;
                bfr[stk][nt][ks] = *(const v8s*)p;
            }
    #pragma unroll
    for (int mt = 0; mt < 4; ++mt) {
        v8s afr[4];
        #pragma unroll
        for (int ks = 0; ks < 4; ++ks) {
            int row = mt * 16 + cl;
            int gr = (ks * 4 + q) ^ (row & 7);
            afr[ks] = *(const v8s*)(xs + row * 256 + (gr << 4));
        }
        v4f acc[2][2];
        #pragma unroll
        for (int stk = 0; stk < 2; ++stk)
            #pragma unroll
            for (int nt = 0; nt < 2; ++nt) {
                v4f a = {0.f, 0.f, 0.f, 0.f};
                #pragma unroll
                for (int ks = 0; ks < 4; ++ks)
                    a = __builtin_amdgcn_mfma_f32_16x16x32_bf16(afr[ks], bfr[stk][nt][ks], a, 0, 0, 0);
                acc[stk][nt] = a;
            }
        #pragma unroll
        for (int nt = 0; nt < 2; ++nt)
            #pragma unroll
            for (int reg = 0; reg < 4; ++reg) {
                int node = b0 + mt * 16 + q * 4 + reg;
                if (node < N_NODES) {
                    int col = colbase + nt * 16 + cl;
                    if (isWr == 0) {
                        float dv = dinv[node];
                        g[(size_t)node * 64 + col] = pack_bf2(dv * acc[0][nt][reg], dv * acc[1][nt][reg]);
                    } else {
                        root[(size_t)node * 64 + col] = pack_bf2(acc[0][nt][reg], acc[1][nt][reg]);
                    }
                }
            }
    }
}

// block = 64 nodes; wave w -> 16-col slice; per-stack A (hk0/hk1), per-stack B.
__global__ void __launch_bounds__(256) dense_mid_mfma(
        const ushort* __restrict__ hk0, const ushort* __restrict__ hk1,
        const ushort* __restrict__ WmT, const float* __restrict__ dinv,
        unsigned* __restrict__ g2) {
    __shared__ char hs[2 * 64 * 128];   // 16KB: [stk][row][64 bf16], swizzled
    int tid = threadIdx.x;
    int b0 = blockIdx.x * 64;
    for (int i = tid; i < 1024; i += 256) {          // 2 tiles * 64 rows * 8 granules
        int stk = i >> 9, rem = i & 511, row = rem >> 3, gr = rem & 7;
        int grow = b0 + row;
        uint4 v = make_uint4(0, 0, 0, 0);
        const ushort* srcp = stk ? hk1 : hk0;
        if (grow < N_NODES) v = *(const uint4*)(srcp + (size_t)grow * 64 + gr * 8);
        *(uint4*)(hs + stk * 8192 + row * 128 + ((gr ^ (row & 7)) << 4)) = v;
    }
    __syncthreads();
    int lane = tid & 63;
    int w = tid >> 6;
    int q = lane >> 4, cl = lane & 15;
    v8s bfr[2][2];   // [stk][kstep]
    #pragma unroll
    for (int stk = 0; stk < 2; ++stk)
        #pragma unroll
        for (int ks = 0; ks < 2; ++ks) {
            const ushort* p = WmT + ((size_t)stk * 64 + w * 16 + cl) * 64 + ks * 32 + q * 8;
            bfr[stk][ks] = *(const v8s*)p;
        }
    #pragma unroll
    for (int mt = 0; mt < 4; ++mt) {
        v4f acc[2];
        #pragma unroll
        for (int stk = 0; stk < 2; ++stk) {
            v4f a = {0.f, 0.f, 0.f, 0.f};
            #pragma unroll
            for (int ks = 0; ks < 2; ++ks) {
                int row = mt * 16 + cl;
                int gr = (ks * 4 + q) ^ (row & 7);
                v8s af = *(const v8s*)(hs + stk * 8192 + row * 128 + (gr << 4));
                a = __builtin_amdgcn_mfma_f32_16x16x32_bf16(af, bfr[stk][ks], a, 0, 0, 0);
            }
            acc[stk] = a;
        }
        #pragma unroll
        for (int reg = 0; reg < 4; ++reg) {
            int node = b0 + mt * 16 + q * 4 + reg;
            if (node < N_NODES) {
                float dv = dinv[node];
                g2[(size_t)node * 64 + w * 16 + cl] = pack_bf2(dv * acc[0][reg], dv * acc[1][reg]);
            }
        }
    }
}

// block = 64 nodes; wave w: matrix (w>>1 ? Wr : Wi), node-half (w&1), both stacks.
__global__ void __launch_bounds__(256) dense_y2_mfma(
        const ushort* __restrict__ yb, const ushort* __restrict__ W2T,
        const float* __restrict__ dinv,
        unsigned* __restrict__ h2, unsigned* __restrict__ root2) {
    __shared__ char ys[64 * 128];   // 8KB: 64 rows x 64 bf16, swizzled
    int tid = threadIdx.x;
    int b0 = blockIdx.x * 64;
    for (int i = tid; i < 512; i += 256) {           // 64 rows * 8 granules
        int row = i >> 3, gr = i & 7;
        int grow = b0 + row;
        uint4 v = make_uint4(0, 0, 0, 0);
        if (grow < N_NODES) v = *(const uint4*)(yb + (size_t)grow * 64 + gr * 8);
        *(uint4*)(ys + row * 128 + ((gr ^ (row & 7)) << 4)) = v;
    }
    __syncthreads();
    int lane = tid & 63;
    int w = tid >> 6;
    int q = lane >> 4, cl = lane & 15;
    int isWr = w >> 1;
    int mbase = (w & 1) * 2;
    v8s bfr[2][2][2];   // [stk][ntile][kstep]
    #pragma unroll
    for (int stk = 0; stk < 2; ++stk)
        #pragma unroll
        for (int nt = 0; nt < 2; ++nt)
            #pragma unroll
            for (int ks = 0; ks < 2; ++ks) {
                const ushort* p = W2T + ((size_t)(isWr * 2 + stk) * 32 + nt * 16 + cl) * 64
                                  + ks * 32 + q * 8;
                bfr[stk][nt][ks] = *(const v8s*)p;
            }
    #pragma unroll
    for (int mi = 0; mi < 2; ++mi) {
        int mt = mbase + mi;
        v8s afr[2];
        #pragma unroll
        for (int ks = 0; ks < 2; ++ks) {
            int row = mt * 16 + cl;
            int gr = (ks * 4 + q) ^ (row & 7);
            afr[ks] = *(const v8s*)(ys + row * 128 + (gr << 4));
        }
        v4f acc[2][2];
        #pragma unroll
        for (int stk = 0; stk < 2; ++stk)
            #pragma unroll
            for (int nt = 0; nt < 2; ++nt) {
                v4f a = {0.f, 0.f, 0.f, 0.f};
                #pragma unroll
                for (int ks = 0; ks < 2; ++ks)
                    a = __builtin_amdgcn_mfma_f32_16x16x32_bf16(afr[ks], bfr[stk][nt][ks], a, 0, 0, 0);
                acc[stk][nt] = a;
            }
        #pragma unroll
        for (int nt = 0; nt < 2; ++nt)
            #pragma unroll
            for (int reg = 0; reg < 4; ++reg) {
                int node = b0 + mt * 16 + q * 4 + reg;
                int col = nt * 16 + cl;
                if (node < N_NODES && col < C) {
                    if (isWr == 0) {
                        float dv = dinv[node];
                        h2[(size_t)node * C + col] = pack_bf2(dv * acc[0][nt][reg], dv * acc[1][nt][reg]);
                    } else {
                        root2[(size_t)node * C + col] = pack_bf2(acc[0][nt][reg], acc[1][nt][reg]);
                    }
                }
            }
    }
}

// block = 64 nodes; wave w -> m-tile w; K=18 pad 32 (1 kstep); both stacks, 2 n-tiles.
__global__ void __launch_bounds__(256) dense_last_mfma(
        const ushort* __restrict__ ok0, const ushort* __restrict__ ok1,
        const ushort* __restrict__ W3T, const float* __restrict__ dinv,
        unsigned* __restrict__ h3) {
    __shared__ char hs[2 * 64 * 64];   // 8KB: [stk][row][32 bf16], swizzled (gr ^ row&3)
    int tid = threadIdx.x;
    int b0 = blockIdx.x * 64;
    for (int i = tid; i < 2048; i += 256) ((unsigned*)hs)[i] = 0;
    __syncthreads();
    for (int i = tid; i < 4096; i += 256) {          // 2 stk * 64 rows * 32 cols
        int stk = i >> 11, row = (i >> 5) & 63, col = i & 31;
        int node = b0 + row;
        if (col < C && node < N_NODES) {
            ushort v = (stk ? ok1 : ok0)[(size_t)node * C + col];
            int gr = (col >> 3) ^ (row & 3);
            *(ushort*)(hs + stk * 4096 + row * 64 + (gr << 4) + (col & 7) * 2) = v;
        }
    }
    __syncthreads();
    int lane = tid & 63;
    int w = tid >> 6;
    int q = lane >> 4, cl = lane & 15;
    v8s bfr[2][2];   // [stk][ntile]
    #pragma unroll
    for (int stk = 0; stk < 2; ++stk)
        #pragma unroll
        for (int nt = 0; nt < 2; ++nt) {
            const ushort* p = W3T + ((size_t)stk * 32 + nt * 16 + cl) * 32 + q * 8;
            bfr[stk][nt] = *(const v8s*)p;
        }
    int row = w * 16 + cl;
    int gr = q ^ (row & 3);
    v8s af0 = *(const v8s*)(hs + row * 64 + (gr << 4));
    v8s af1 = *(const v8s*)(hs + 4096 + row * 64 + (gr << 4));
    v4f acc[2][2];
    #pragma unroll
    for (int nt = 0; nt < 2; ++nt) {
        acc[0][nt] = __builtin_amdgcn_mfma_f32_16x16x32_bf16(af0, bfr[0][nt], (v4f){0.f,0.f,0.f,0.f}, 0, 0, 0);
        acc[1][nt] = __builtin_amdgcn_mfma_f32_16x16x32_bf16(af1, bfr[1][nt], (v4f){0.f,0.f,0.f,0.f}, 0, 0, 0);
    }
    #pragma unroll
    for (int nt = 0; nt < 2; ++nt)
        #pragma unroll
        for (int reg = 0; reg < 4; ++reg) {
            int node = b0 + w * 16 + q * 4 + reg;
            int col = nt * 16 + cl;
            if (node < N_NODES && col < C) {
                float dv = dinv[node];
                h3[(size_t)node * C + col] = pack_bf2(dv * acc[0][nt][reg], dv * acc[1][nt][reg]);
            }
        }
}

// ----------------- propagation (gather over CSR, bf16x2 stacks) -----------------

template <int FINAL>
__global__ void __launch_bounds__(256) prop64_kernel(
        const unsigned* __restrict__ g, const unsigned* __restrict__ root,
        const float* __restrict__ b, const float* __restrict__ dinv,
        const int* __restrict__ rp, const int* __restrict__ ssrc,
        ushort* __restrict__ ok0, ushort* __restrict__ ok1, ushort* __restrict__ yb) {
    int lane = threadIdx.x & 63;
    int wid = __builtin_amdgcn_readfirstlane((int)((blockIdx.x * 256 + threadIdx.x) >> 6));
    if (wid >= N_NODES) return;
    int e0 = rp[wid], e1 = rp[wid + 1];
    float a0 = 0.f, a1 = 0.f;
    int e = e0;
    for (; e + 4 <= e1; e += 4) {
        int s0 = ssrc[e], s1 = ssrc[e + 1], s2 = ssrc[e + 2], s3 = ssrc[e + 3];
        unsigned u0 = g[(size_t)s0 * H + lane];
        unsigned u1 = g[(size_t)s1 * H + lane];
        unsigned u2 = g[(size_t)s2 * H + lane];
        unsigned u3 = g[(size_t)s3 * H + lane];
        float2 v0 = unpack_bf2(u0), v1 = unpack_bf2(u1);
        float2 v2 = unpack_bf2(u2), v3 = unpack_bf2(u3);
        a0 += (v0.x + v1.x) + (v2.x + v3.x);
        a1 += (v0.y + v1.y) + (v2.y + v3.y);
    }
    for (; e < e1; ++e) {
        float2 v = unpack_bf2(g[(size_t)ssrc[e] * H + lane]);
        a0 += v.x; a1 += v.y;
    }
    float dv = dinv[wid];
    float2 rt = unpack_bf2(root[(size_t)wid * H + lane]);
    float o0 = fmaxf(fmaf(dv, a0, rt.x + b[lane]), 0.f);
    float o1 = fmaxf(fmaf(dv, a1, rt.y + b[H + lane]), 0.f);
    if (FINAL) {
        yb[(size_t)wid * H + lane] = (ushort)bf16_rne(0.5f * (o0 + o1));
    } else {
        ok0[(size_t)wid * H + lane] = (ushort)bf16_rne(o0);
        ok1[(size_t)wid * H + lane] = (ushort)bf16_rne(o1);
    }
}

template <int FINAL>
__global__ void __launch_bounds__(256) prop18_kernel(
        const unsigned* __restrict__ g, const unsigned* __restrict__ root,
        const float* __restrict__ b, const float* __restrict__ dinv,
        const int* __restrict__ rp, const int* __restrict__ ssrc,
        ushort* __restrict__ ok0, ushort* __restrict__ ok1, float* __restrict__ outp) {
    int lane = threadIdx.x & 63;
    int wid = __builtin_amdgcn_readfirstlane((int)((blockIdx.x * 256 + threadIdx.x) >> 6));
    if (wid >= N_NODES) return;
    int e0 = rp[wid], e1 = rp[wid + 1];
    bool act = lane < C;
    int c = act ? lane : 0;
    float a0 = 0.f, a1 = 0.f;
    int e = e0;
    for (; e + 4 <= e1; e += 4) {
        int s0 = ssrc[e], s1 = ssrc[e + 1], s2 = ssrc[e + 2], s3 = ssrc[e + 3];
        unsigned u0 = g[(size_t)s0 * C + c];
        unsigned u1 = g[(size_t)s1 * C + c];
        unsigned u2 = g[(size_t)s2 * C + c];
        unsigned u3 = g[(size_t)s3 * C + c];
        float2 v0 = unpack_bf2(u0), v1 = unpack_bf2(u1);
        float2 v2 = unpack_bf2(u2), v3 = unpack_bf2(u3);
        if (act) {
            a0 += (v0.x + v1.x) + (v2.x + v3.x);
            a1 += (v0.y + v1.y) + (v2.y + v3.y);
        }
    }
    for (; e < e1; ++e) {
        float2 v = unpack_bf2(g[(size_t)ssrc[e] * C + c]);
        if (act) { a0 += v.x; a1 += v.y; }
    }
    float dv = dinv[wid];
    float o0 = 0.f, o1 = 0.f;
    if (act) {
        float2 rt = unpack_bf2(root[(size_t)wid * C + c]);
        o0 = fmaxf(fmaf(dv, a0, rt.x + b[c]), 0.f);
        o1 = fmaxf(fmaf(dv, a1, rt.y + b[C + c]), 0.f);
    }
    if (!FINAL) {
        if (act) {
            ok0[(size_t)wid * C + c] = (ushort)bf16_rne(o0);
            ok1[(size_t)wid * C + c] = (ushort)bf16_rne(o1);
        }
    } else {
        float m = act ? 0.5f * (o0 + o1) : -INFINITY;
        float mx = m;
        #pragma unroll
        for (int off = 16; off >= 1; off >>= 1) mx = fmaxf(mx, __shfl_xor(mx, off, 64));
        float ex = act ? __expf(m - mx) : 0.f;
        float sum = ex;
        #pragma unroll
        for (int off = 16; off >= 1; off >>= 1) sum += __shfl_xor(sum, off, 64);
        if (act) outp[(size_t)wid * C + c] = m - mx - logf(sum);
    }
}

// ----------------- launch -----------------

extern "C" void kernel_launch(void* const* d_in, const int* in_sizes, int n_in,
                              void* d_out, int out_size, void* d_ws, size_t ws_size,
                              hipStream_t stream) {
    const float* x        = (const float*)d_in[0];
    const int*   ei       = (const int*)d_in[1];
    const float* init_w1  = (const float*)d_in[2];
    const float* w1       = (const float*)d_in[3];
    const float* root_w1  = (const float*)d_in[4];
    const float* b1       = (const float*)d_in[5];
    const float* init_w2  = (const float*)d_in[6];
    const float* w2       = (const float*)d_in[7];
    const float* root_w2  = (const float*)d_in[8];
    const float* b2       = (const float*)d_in[9];
    const int* src = ei;
    const int* tgt = ei + N_EDGES;
    float* out = (float*)d_out;

    char* w = (char*)d_ws;
    size_t off = 0;
    auto alloc = [&](size_t bytes) -> char* {
        char* p = w + off;
        off += (bytes + 255) & ~(size_t)255;
        return p;
    };
    int*      rp    = (int*)alloc((size_t)(N_NODES + 1) * 4);
    float*    dinv  = (float*)alloc((size_t)N_NODES * 4);
    int*      bsum  = (int*)alloc(512 * 4);
    int*      hist  = (int*)alloc((size_t)NBUCKETS * NBLK * 4);
    int*      histx = (int*)alloc((size_t)NBUCKETS * NBLK * 4);
    unsigned* tmp   = (unsigned*)alloc((size_t)N_EDGES * 4);
    int*      ssrc  = (int*)alloc((size_t)N_EDGES * 4);
    ushort*   xb    = (ushort*)alloc((size_t)N_NODES * 128 * 2);  // 25.6 MB
    ushort*   W1T   = (ushort*)alloc((size_t)4 * 64 * 128 * 2);
    ushort*   WmT   = (ushort*)alloc((size_t)2 * 64 * 64 * 2);
    ushort*   W2T   = (ushort*)alloc((size_t)4 * 32 * 64 * 2);
    ushort*   W3T   = (ushort*)alloc((size_t)2 * 32 * 32 * 2);
    unsigned* g1    = (unsigned*)alloc((size_t)N_NODES * H * 4);  // 25.6 MB
    unsigned* root1 = (unsigned*)alloc((size_t)N_NODES * H * 4);  // 25.6 MB
    ushort*   hk0   = (ushort*)alloc((size_t)N_NODES * H * 2);    // 12.8 MB
    ushort*   hk1   = (ushort*)alloc((size_t)N_NODES * H * 2);    // 12.8 MB
    unsigned* g2    = (unsigned*)alloc((size_t)N_NODES * H * 4);  // 25.6 MB
    ushort*   yb    = (ushort*)alloc((size_t)N_NODES * H * 2);    // 12.8 MB
    // layer-2 overlays (lifetimes disjoint)
    unsigned* h2u    = g1;                                   // [N*C] u32
    unsigned* root2u = g1 + (size_t)N_NODES * C;             // [N*C] u32
    unsigned* h3u    = g1 + (size_t)2 * N_NODES * C;         // [N*C] u32
    ushort*   p18k0  = (ushort*)root1;                       // [N*C] bf16
    ushort*   p18k1  = (ushort*)root1 + (size_t)N_NODES * C; // [N*C] bf16

    int nbH = (NBUCKETS * NBLK + 255) / 256;         // 391

    // ---- CSR build: zero global atomics ----
    histA_kernel<<<NBLK, 256, 0, stream>>>(tgt, hist);
    scan1_kernel<<<nbH, 256, 0, stream>>>(hist, histx, bsum, NBUCKETS * NBLK);
    scan2_kernel<<<1, 64, 0, stream>>>(bsum, nbH);
    scan3_kernel<<<nbH, 256, 0, stream>>>(histx, bsum, NBUCKETS * NBLK, -1);
    scatterC_kernel<<<NBLK, 256, 0, stream>>>(src, tgt, histx, tmp);
    bucketD2_kernel<<<NBUCKETS, 256, 0, stream>>>(tmp, histx, rp, dinv, ssrc);

    convert_x_kernel<<<(N_NODES * 64 + 255) / 256, 256, 0, stream>>>(x, (unsigned*)xb);
    prep_w1_kernel<<<128, 256, 0, stream>>>(init_w1, root_w1, W1T);
    prep_wmid_kernel<<<32, 256, 0, stream>>>(w1, WmT);
    prep_w2_kernel<<<32, 256, 0, stream>>>(init_w2, root_w2, W2T);
    prep_w3_kernel<<<8, 256, 0, stream>>>(w2, W3T);

    int gblocks = (N_NODES + 63) / 64;          // 1563
    int pgrid   = (N_NODES + 3) / 4;            // 25000 (wave per node)

    // ---- layer 1 (F_IN=100 -> H=64) ----
    dense1_mfma<<<gblocks, 256, 0, stream>>>(xb, W1T, dinv, g1, root1);
    prop64_kernel<0><<<pgrid, 256, 0, stream>>>(g1, root1, b1, dinv, rp, ssrc, hk0, hk1, nullptr);
    dense_mid_mfma<<<gblocks, 256, 0, stream>>>(hk0, hk1, WmT, dinv, g2);
    prop64_kernel<1><<<pgrid, 256, 0, stream>>>(g2, root1, b1, dinv, rp, ssrc, nullptr, nullptr, yb);

    // ---- layer 2 (H=64 -> C=18) ----
    dense_y2_mfma<<<gblocks, 256, 0, stream>>>(yb, W2T, dinv, h2u, root2u);
    prop18_kernel<0><<<pgrid, 256, 0, stream>>>(h2u, root2u, b2, dinv, rp, ssrc, p18k0, p18k1, nullptr);
    dense_last_mfma<<<gblocks, 256, 0, stream>>>(p18k0, p18k1, W3T, dinv, h3u);
    prop18_kernel<1><<<pgrid, 256, 0, stream>>>(h3u, root2u, b2, dinv, rp, ssrc, nullptr, nullptr, out);
}